// Round 8
// baseline (285.024 us; speedup 1.0000x reference)
//
#include <hip/hip_runtime.h>
#include <hip/hip_bf16.h>
#include <cstdint>
#include <cstddef>

#define BB 128
#define NN 300
#define EE 300
#define DIN 768
#define DH 256
#define NREL 26
#define NHEADS 8
#define HDIM 32
#define MTOT (BB*NN)    // 38400
#define NEDGE (BB*EE)   // 38400
#define NHB 150         // histogram blocks (150*256 == NEDGE)

typedef __attribute__((ext_vector_type(8))) short bf16x8;
typedef __attribute__((ext_vector_type(4))) float f32x4;
typedef unsigned short u16;
union BU { uint4 u; bf16x8 v; };

__device__ __forceinline__ unsigned int packbf2(float a, float b) {
    unsigned int ua = __float_as_uint(a);
    unsigned int ub = __float_as_uint(b);
    ua = (ua + 0x7FFFu + ((ua >> 16) & 1u)) >> 16;
    ub = (ub + 0x7FFFu + ((ub >> 16) & 1u)) & 0xFFFF0000u;
    return ua | ub;
}
__device__ __forceinline__ u16 packbf1(float a) {
    unsigned int ua = __float_as_uint(a);
    return (u16)((ua + 0x7FFFu + ((ua >> 16) & 1u)) >> 16);
}
__device__ __forceinline__ unsigned cvtpk(float a, float b) {
    union { __hip_bfloat162 h; unsigned u; } cv;
    cv.h = __float22bfloat162_rn(make_float2(a, b));   // v_cvt_pk_bf16_f32
    return cv.u;
}

// ---------------- atomic-free edge bucketing (counting sort by relation) ----------------
__global__ __launch_bounds__(256) void b_hist(const int* __restrict__ etype,
                                              int* __restrict__ blockhist) {
    __shared__ int hist[NREL];
    const int tid = threadIdx.x;
    if (tid < NREL) hist[tid] = 0;
    __syncthreads();
    atomicAdd(&hist[etype[blockIdx.x * 256 + tid]], 1);   // LDS atomic
    __syncthreads();
    if (tid < NREL) blockhist[blockIdx.x * NREL + tid] = hist[tid];
}

__global__ __launch_bounds__(64) void b_scan(const int* __restrict__ blockhist,
                                             int* __restrict__ blockbase,
                                             int* __restrict__ cnt, int* __restrict__ off) {
    __shared__ int tot[NREL];
    const int r = threadIdx.x;
    if (r < NREL) {
        int run = 0;
        for (int b = 0; b < NHB; ++b) {
            blockbase[b * NREL + r] = run;
            run += blockhist[b * NREL + r];
        }
        tot[r] = run;
        cnt[r] = run;
    }
    __syncthreads();
    __shared__ int offs[NREL + 1];
    if (r == 0) {
        int acc = 0;
        for (int q = 0; q < NREL; ++q) { offs[q] = acc; off[q] = acc; acc += tot[q]; }
        offs[NREL] = acc; off[NREL] = acc;
    }
    __syncthreads();
    if (r < NREL) {
        int o = offs[r];
        for (int b = 0; b < NHB; ++b) blockbase[b * NREL + r] += o;
    }
}

__global__ __launch_bounds__(256) void b_scatter(const int* __restrict__ etype,
                                                 const int* __restrict__ blockbase,
                                                 int* __restrict__ list) {
    __shared__ int wavehist[4][NREL];
    __shared__ int waveoff[4][NREL];
    const int tid = threadIdx.x;
    const int w = tid >> 6, l = tid & 63;
    const int i = blockIdx.x * 256 + tid;
    const int r = etype[i];
    unsigned long long mymask = 0ull;
    #pragma unroll
    for (int q = 0; q < NREL; ++q) {
        unsigned long long m = __ballot(r == q);
        if (l == 0) wavehist[w][q] = __popcll(m);
        if (r == q) mymask = m;
    }
    const int myrank = __popcll(mymask & ((1ull << l) - 1ull));
    __syncthreads();
    if (tid < NREL) {
        int acc = 0;
        #pragma unroll
        for (int ww = 0; ww < 4; ++ww) { waveoff[ww][tid] = acc; acc += wavehist[ww][tid]; }
    }
    __syncthreads();
    list[blockbase[blockIdx.x * NREL + r] + waveoff[w][r] + myrank] = i;
}

// ---------------- zero V-tail fragment chunks (jn>=300 slots live only in
// chunks 9 and 19 per (b,head)); k3m then overwrites the valid jn=288..299 part.
__global__ __launch_bounds__(128) void z_tail(uint4* __restrict__ vg4) {
    const int p = blockIdx.x;            // (b*8+hh), 1024 total
    const int tid = threadIdx.x;
    const int f = (tid < 64) ? 9 : 19;
    const int t = tid & 63;
    vg4[(size_t)(p * 20 + f) * 64 + t] = make_uint4(0u, 0u, 0u, 0u);
}

// ---------------- casts ----------------
__global__ __launch_bounds__(256) void c_cast8(const float4* __restrict__ in,
                                               uint4* __restrict__ out, int n8) {
    int i = blockIdx.x * 256 + threadIdx.x;
    if (i < n8) {
        float4 f0 = in[2*i], f1 = in[2*i+1];
        uint4 o;
        o.x = packbf2(f0.x, f0.y); o.y = packbf2(f0.z, f0.w);
        o.z = packbf2(f1.x, f1.y); o.w = packbf2(f1.z, f1.w);
        out[i] = o;
    }
}

// Pack weights into MFMA B-fragment order.
__global__ __launch_bounds__(256) void c_cast_w(
    const float* __restrict__ wrel, const float* __restrict__ wl, const float* __restrict__ wq,
    uint4* __restrict__ wrb, uint4* __restrict__ wlb, uint4* __restrict__ wqb) {
    int t = blockIdx.x * 256 + threadIdx.x;
    int l = t & 63, fid = t >> 6;
    if (fid < NREL*24*16) {
        int r = fid / 384, rem = fid - r * 384;
        int kf = rem >> 4, nt = rem & 15;
        int k0 = 32*kf + 8*(l >> 4), n = 16*nt + (l & 15);
        const float* p = wrel + ((size_t)r*768 + k0) * 256 + n;
        uint4 o;
        o.x = packbf2(p[0], p[256]); o.y = packbf2(p[512], p[768]);
        o.z = packbf2(p[1024], p[1280]); o.w = packbf2(p[1536], p[1792]);
        wrb[t] = o;
    } else if (fid < NREL*24*16 + 384) {
        int f2 = fid - NREL*24*16;
        int kf = f2 >> 4, nt = f2 & 15;
        int k0 = 32*kf + 8*(l >> 4), n = 16*nt + (l & 15);
        const float* p = wl + (size_t)k0 * 256 + n;
        uint4 o;
        o.x = packbf2(p[0], p[256]); o.y = packbf2(p[512], p[768]);
        o.z = packbf2(p[1024], p[1280]); o.w = packbf2(p[1536], p[1792]);
        wlb[f2*64 + l] = o;
    } else {
        int f2 = fid - NREL*24*16 - 384;   // kf*48 + nt
        int kf = f2 / 48, nt = f2 % 48;
        int e = 16*nt + (l & 15), d0 = 32*kf + 8*(l >> 4);
        const float4* p = (const float4*)(wq + (size_t)e * 256 + d0);
        float4 f0 = p[0], f1 = p[1];
        uint4 o;
        o.x = packbf2(f0.x, f0.y); o.y = packbf2(f0.z, f0.w);
        o.z = packbf2(f1.x, f1.y); o.w = packbf2(f1.z, f1.w);
        wqb[f2*64 + l] = o;
    }
}

// ---------------- MFMA GEMM: h = xb @ wlb + b_rel  (M=128 x N=128 tile) ----------------
__global__ __launch_bounds__(256) void k1m(
    const uint4* __restrict__ xb, const uint4* __restrict__ wlb,
    const float* __restrict__ brel, float* __restrict__ h) {
    __shared__ uint4 As[1024];          // 16KB: 128 rows x K64, frag order [kf2][mt8][l64]
    const int tid = threadIdx.x;
    const int m0 = blockIdx.x * 128;
    const int nb = blockIdx.y;
    const int w = tid >> 6, l = tid & 63;
    const int g = l >> 4, q = l & 15;
    int cA[4];
    #pragma unroll
    for (int p = 0; p < 4; ++p) {
        int s = tid + p * 256;
        int fi = s >> 6, l2 = s & 63;
        int kf = fi >> 3, mt = fi & 7;
        int row = m0 + 16*mt + (l2 & 15);
        cA[p] = row * 96 + 4*kf + (l2 >> 4);
    }
    f32x4 acc[8][2];
    #pragma unroll
    for (int a = 0; a < 8; ++a)
        #pragma unroll
        for (int n = 0; n < 2; ++n) acc[a][n] = (f32x4){0.f,0.f,0.f,0.f};

    for (int step = 0; step < 12; ++step) {
        uint4 a0 = xb[cA[0] + step*8];
        uint4 a1 = xb[cA[1] + step*8];
        uint4 a2 = xb[cA[2] + step*8];
        uint4 a3 = xb[cA[3] + step*8];
        BU Bf[2][2];
        #pragma unroll
        for (int kf = 0; kf < 2; ++kf)
            #pragma unroll
            for (int nt = 0; nt < 2; ++nt)
                Bf[kf][nt].u = wlb[((step*2 + kf)*16 + nb*8 + w*2 + nt)*64 + l];
        __syncthreads();
        As[tid] = a0; As[tid + 256] = a1; As[tid + 512] = a2; As[tid + 768] = a3;
        __syncthreads();
        #pragma unroll
        for (int kf = 0; kf < 2; ++kf) {
            #pragma unroll
            for (int mt = 0; mt < 8; ++mt) {
                BU Af; Af.u = As[(kf*8 + mt)*64 + l];
                #pragma unroll
                for (int nt = 0; nt < 2; ++nt)
                    acc[mt][nt] = __builtin_amdgcn_mfma_f32_16x16x32_bf16(Af.v, Bf[kf][nt].v, acc[mt][nt], 0, 0, 0);
            }
        }
    }
    #pragma unroll
    for (int nt = 0; nt < 2; ++nt) {
        int col = nb*128 + w*32 + nt*16 + q;
        float bias = brel[col];
        #pragma unroll
        for (int mt = 0; mt < 8; ++mt)
            #pragma unroll
            for (int i = 0; i < 4; ++i)
                h[(size_t)(m0 + 16*mt + 4*g + i)*256 + col] = acc[mt][nt][i] + bias;
    }
}

// ------- MFMA per-relation msg GEMM + scatter-add (M=128 edges/block) -------
__global__ __launch_bounds__(256) void k2m(
    const uint4* __restrict__ xb, const uint4* __restrict__ wrb,
    const int* __restrict__ src, const int* __restrict__ dst,
    const int* __restrict__ cnt, const int* __restrict__ off,
    const int* __restrict__ list, float* __restrict__ h) {
    __shared__ uint4 As[1024];
    __shared__ int arow_s[128];
    __shared__ int drow_s[128];
    const int r = blockIdx.y;
    const int c_total = cnt[r];
    const int t0 = blockIdx.x * 128;
    if (t0 >= c_total) return;
    const int nb = blockIdx.z;
    const int tid = threadIdx.x;
    if (tid < 128) {
        int e = t0 + tid;
        int ar = 0, dr = -1;
        if (e < c_total) {
            int eid = list[off[r] + e];
            int b = eid / EE;
            ar = b * NN + src[eid];
            dr = b * NN + dst[eid];
        }
        arow_s[tid] = ar; drow_s[tid] = dr;
    }
    __syncthreads();
    const int w = tid >> 6, l = tid & 63;
    const int g = l >> 4, q = l & 15;
    int cA[4];
    #pragma unroll
    for (int p = 0; p < 4; ++p) {
        int s = tid + p * 256;
        int fi = s >> 6, l2 = s & 63;
        int kf = fi >> 3, mt = fi & 7;
        int row = arow_s[16*mt + (l2 & 15)];
        cA[p] = row * 96 + 4*kf + (l2 >> 4);
    }
    const uint4* wb = wrb + (size_t)r * 24*16*64;
    f32x4 acc[8][2];
    #pragma unroll
    for (int a = 0; a < 8; ++a)
        #pragma unroll
        for (int n = 0; n < 2; ++n) acc[a][n] = (f32x4){0.f,0.f,0.f,0.f};

    for (int step = 0; step < 12; ++step) {
        uint4 a0 = xb[cA[0] + step*8];
        uint4 a1 = xb[cA[1] + step*8];
        uint4 a2 = xb[cA[2] + step*8];
        uint4 a3 = xb[cA[3] + step*8];
        BU Bf[2][2];
        #pragma unroll
        for (int kf = 0; kf < 2; ++kf)
            #pragma unroll
            for (int nt = 0; nt < 2; ++nt)
                Bf[kf][nt].u = wb[((step*2 + kf)*16 + nb*8 + w*2 + nt)*64 + l];
        __syncthreads();
        As[tid] = a0; As[tid + 256] = a1; As[tid + 512] = a2; As[tid + 768] = a3;
        __syncthreads();
        #pragma unroll
        for (int kf = 0; kf < 2; ++kf) {
            #pragma unroll
            for (int mt = 0; mt < 8; ++mt) {
                BU Af; Af.u = As[(kf*8 + mt)*64 + l];
                #pragma unroll
                for (int nt = 0; nt < 2; ++nt)
                    acc[mt][nt] = __builtin_amdgcn_mfma_f32_16x16x32_bf16(Af.v, Bf[kf][nt].v, acc[mt][nt], 0, 0, 0);
            }
        }
    }
    #pragma unroll
    for (int mt = 0; mt < 8; ++mt)
        #pragma unroll
        for (int i = 0; i < 4; ++i) {
            int dr = drow_s[16*mt + 4*g + i];
            if (dr >= 0) {
                #pragma unroll
                for (int nt = 0; nt < 2; ++nt)
                    atomicAdd(&h[(size_t)dr*256 + nb*128 + w*32 + nt*16 + q], acc[mt][nt][i]);
            }
        }
}

// ---------------- MFMA qkv projection, fused f32->bf16 A-cast, persistent A in LDS,
// internal nb loop (B is L2-resident 384KB). Outputs in MFMA fragment order (see R4).
__global__ __launch_bounds__(256) void k3m(
    const float* __restrict__ h, const uint4* __restrict__ wqb,
    const float* __restrict__ bq,
    u16* __restrict__ qg, u16* __restrict__ kg, u16* __restrict__ vg) {
    __shared__ uint4 Aall[2048];   // 32KB: 64 rows x K256 bf16, frag order [kf8][mt4][l64]
    const int tid = threadIdx.x;
    const int m0 = blockIdx.x * 64;
    const int w = tid >> 6, l = tid & 63;
    const int g = l >> 4, q = l & 15;

    // stage ALL of A once, casting f32 -> bf16 into fragment order
    #pragma unroll
    for (int p = 0; p < 8; ++p) {
        int s = tid + p * 256;
        int fi = s >> 6, l2 = s & 63;
        int kf = fi >> 2, mt = fi & 3;
        int row = m0 + 16*mt + (l2 & 15);
        int k0 = 32*kf + 8*(l2 >> 4);
        const float4* hp = (const float4*)(h + (size_t)row * 256 + k0);
        float4 f0 = hp[0], f1 = hp[1];
        uint4 o;
        o.x = packbf2(f0.x, f0.y); o.y = packbf2(f0.z, f0.w);
        o.z = packbf2(f1.x, f1.y); o.w = packbf2(f1.z, f1.w);
        Aall[s] = o;
    }
    __syncthreads();

    for (int nb = 0; nb < 6; ++nb) {
        f32x4 acc[4][2];
        #pragma unroll
        for (int a = 0; a < 4; ++a)
            #pragma unroll
            for (int n = 0; n < 2; ++n) acc[a][n] = (f32x4){0.f,0.f,0.f,0.f};

        #pragma unroll
        for (int step = 0; step < 4; ++step) {
            BU Bf[2][2];
            #pragma unroll
            for (int kf = 0; kf < 2; ++kf)
                #pragma unroll
                for (int nt = 0; nt < 2; ++nt)
                    Bf[kf][nt].u = wqb[((step*2 + kf)*48 + nb*8 + w*2 + nt)*64 + l];
            #pragma unroll
            for (int kf = 0; kf < 2; ++kf) {
                #pragma unroll
                for (int mt = 0; mt < 4; ++mt) {
                    BU Af; Af.u = Aall[((step*2 + kf)*4 + mt)*64 + l];
                    #pragma unroll
                    for (int nt = 0; nt < 2; ++nt)
                        acc[mt][nt] = __builtin_amdgcn_mfma_f32_16x16x32_bf16(Af.v, Bf[kf][nt].v, acc[mt][nt], 0, 0, 0);
                }
            }
        }
        #pragma unroll
        for (int nt = 0; nt < 2; ++nt) {
            int e = nb*128 + w*32 + nt*16 + q;
            float bias = bq[e];
            int region = e >> 8;              // 0=Q,1=K,2=V
            int hh = (e & 255) >> 5;
            int d  = e & 31;
            u16* outb = (region == 0) ? qg : (region == 1) ? kg : vg;
            #pragma unroll
            for (int mt = 0; mt < 4; ++mt) {
                #pragma unroll
                for (int i = 0; i < 4; ++i) {
                    int j = m0 + 16*mt + 4*g + i;
                    int b_ = j / 300;
                    int jn = j - b_ * 300;
                    u16 val = packbf1(acc[mt][nt][i] + bias);
                    size_t byte;
                    if (region < 2) {
                        int word = ((b_*8 + hh)*19 + (jn >> 4))*64 + 16*(d >> 3) + (jn & 15);
                        byte = (size_t)word*16 + (size_t)(d & 7)*2;
                    } else {
                        int word = ((b_*8 + hh)*20 + (d >> 4)*10 + (jn >> 5))*64 + 16*((jn >> 3) & 3) + (d & 15);
                        byte = (size_t)word*16 + (size_t)(jn & 7)*2;
                    }
                    *(u16*)((char*)outb + byte) = val;
                }
            }
        }
    }
}

// ------- MFMA flash attention, no-max softmax (exp2 direct), batched P-transpose -------
__global__ __launch_bounds__(256) void k4_attn(
    const uint4* __restrict__ qg, const uint4* __restrict__ kg,
    const uint4* __restrict__ vg, float* __restrict__ pooled) {
    __shared__ uint4 kf_s[19*64];
    __shared__ uint4 vt_s[20*64];
    __shared__ __align__(16) u16 pbuf[4][2560];   // 5KB per wave: 5 chunks x 1KB
    __shared__ float pool_lds[4][32];
    const int bh = blockIdx.x;
    const int tid = threadIdx.x;
    for (int s = tid; s < 19*64; s += 256) kf_s[s] = kg[(size_t)bh*19*64 + s];
    for (int s = tid; s < 20*64; s += 256) vt_s[s] = vg[(size_t)bh*20*64 + s];
    __syncthreads();

    const int w = tid >> 6, l = tid & 63;
    const int g = l >> 4, q = l & 15;
    char* pwbase = (char*)pbuf[w] + 256*(g >> 1) + 16*q + 8*(g & 1);
    const uint4* prd = (const uint4*)pbuf[w];

    const float c1 = 0.17677669529663687f * 1.4426950408889634f;  // (1/sqrt(32))*log2(e)
    float pool[8] = {0.f,0.f,0.f,0.f,0.f,0.f,0.f,0.f};

    for (int qt = w; qt < 19; qt += 4) {
        const int qrow = qt * 16 + q;
        BU uq; uq.u = qg[(size_t)(bh*19 + qt)*64 + l];
        float lsum = 0.f;
        f32x4 ctx0 = {0.f,0.f,0.f,0.f}, ctx1 = {0.f,0.f,0.f,0.f};

        #pragma unroll
        for (int half = 0; half < 2; ++half) {
            #pragma unroll
            for (int jj = 0; jj < 10; ++jj) {
                const int jt = half*10 + jj;
                uint2 pk = make_uint2(0u, 0u);
                if (jt < 19) {
                    BU uk; uk.u = kf_s[jt*64 + l];
                    f32x4 z = {0.f,0.f,0.f,0.f};
                    f32x4 s4 = __builtin_amdgcn_mfma_f32_16x16x32_bf16(uk.v, uq.v, z, 0, 0, 0);
                    float p0 = exp2f(s4[0]*c1);
                    float p1 = exp2f(s4[1]*c1);
                    float p2 = exp2f(s4[2]*c1);
                    float p3 = exp2f(s4[3]*c1);
                    if (jt == 18 && g == 3) { p0 = 0.f; p1 = 0.f; p2 = 0.f; p3 = 0.f; }
                    lsum += (p0 + p1) + (p2 + p3);
                    pk.x = cvtpk(p0, p1);
                    pk.y = cvtpk(p2, p3);
                }
                *(uint2*)(pwbase + 512*jj) = pk;
            }
            #pragma unroll
            for (int cc = 0; cc < 5; ++cc) {
                const int cg = half*5 + cc;
                BU up;  up.u  = prd[cc*64 + l];
                BU uv0; uv0.u = vt_s[cg*64 + l];
                BU uv1; uv1.u = vt_s[(10 + cg)*64 + l];
                ctx0 = __builtin_amdgcn_mfma_f32_16x16x32_bf16(uv0.v, up.v, ctx0, 0, 0, 0);
                ctx1 = __builtin_amdgcn_mfma_f32_16x16x32_bf16(uv1.v, up.v, ctx1, 0, 0, 0);
            }
        }
        lsum += __shfl_xor(lsum, 16);
        lsum += __shfl_xor(lsum, 32);
        if (qrow < NN) {
            float inv = 1.0f / lsum;
            pool[0] += ctx0[0] * inv; pool[1] += ctx0[1] * inv;
            pool[2] += ctx0[2] * inv; pool[3] += ctx0[3] * inv;
            pool[4] += ctx1[0] * inv; pool[5] += ctx1[1] * inv;
            pool[6] += ctx1[2] * inv; pool[7] += ctx1[3] * inv;
        }
    }

    #pragma unroll
    for (int i = 0; i < 8; ++i) {
        float v = pool[i];
        v += __shfl_xor(v, 1); v += __shfl_xor(v, 2);
        v += __shfl_xor(v, 4); v += __shfl_xor(v, 8);
        pool[i] = v;
    }
    if (q == 0) {
        #pragma unroll
        for (int dt = 0; dt < 2; ++dt)
            #pragma unroll
            for (int i = 0; i < 4; ++i)
                pool_lds[w][dt * 16 + 4 * g + i] = pool[dt * 4 + i];
    }
    __syncthreads();
    if (tid < 32) {
        int b = bh >> 3, hh = bh & 7;
        float s = pool_lds[0][tid] + pool_lds[1][tid] + pool_lds[2][tid] + pool_lds[3][tid];
        pooled[(size_t)b * DH + hh * HDIM + tid] = s * (1.0f / 300.0f);
    }
}

// ------- out = ((pooled @ out_proj^T + bo) @ mlp^T + bm) -------
__global__ __launch_bounds__(256) void k5_head(
    const float* __restrict__ pooled, const float* __restrict__ wo, const float* __restrict__ bo,
    const float* __restrict__ wm, const float* __restrict__ bm, float* __restrict__ out) {
    __shared__ float pc[DH];
    __shared__ float t1[DH];
    const int b = blockIdx.x, tid = threadIdx.x;
    pc[tid] = pooled[(size_t)b * DH + tid];
    __syncthreads();
    float acc = bo[tid];
    for (int d = 0; d < DH; ++d) acc += pc[d] * wo[(size_t)tid * DH + d];
    t1[tid] = acc;
    __syncthreads();
    float acc2 = bm[tid];
    for (int e2 = 0; e2 < DH; ++e2) acc2 += t1[e2] * wm[(size_t)tid * DH + e2];
    out[(size_t)b * DH + tid] = acc2;
}

extern "C" void kernel_launch(void* const* d_in, const int* in_sizes, int n_in,
                              void* d_out, int out_size, void* d_ws, size_t ws_size,
                              hipStream_t stream) {
    (void)in_sizes; (void)n_in; (void)out_size; (void)ws_size;
    const float* x     = (const float*)d_in[0];
    const int*   src   = (const int*)d_in[1];
    const int*   dst   = (const int*)d_in[2];
    const int*   etype = (const int*)d_in[3];
    const float* wrel  = (const float*)d_in[4];
    const float* wloop = (const float*)d_in[5];
    const float* brel  = (const float*)d_in[6];
    const float* wq    = (const float*)d_in[7];
    const float* bq    = (const float*)d_in[8];
    const float* wo    = (const float*)d_in[9];
    const float* bo    = (const float*)d_in[10];
    const float* wm    = (const float*)d_in[11];
    const float* bm    = (const float*)d_in[12];
    float* out = (float*)d_out;

    char* W = (char*)d_ws;
    float* h      = (float*)W;                          // 39,321,600 B (read by k3m; vg aliases after)
    u16*   vg     = (u16*)W;                            // NOTE: vg aliases h! see below
    u16*   xb     = (u16*)(W + 39321600ull);            // 58,982,400 B (dead after k2m)
    u16*   qg     = xb;                                 // 19,922,944 B
    u16*   kg     = (u16*)(W + 39321600ull + 19922944ull);  // 19,922,944 B
    u16*   hb_dead= (u16*)(W + 39321600ull + 58982400ull);  // (unused now)
    uint4* wrb    = (uint4*)(W + 39321600ull + 58982400ull + 19660800ull);  // 10,223,616
    uint4* wlb    = (uint4*)((char*)wrb + 10223616ull);
    uint4* wqb    = (uint4*)((char*)wlb + 393216ull);
    float* pooled = (float*)((char*)wqb + 393216ull);
    int*   ibase  = (int*)((char*)pooled + 131072ull);
    int*   cnt    = ibase;                               // 32
    int*   off    = ibase + 32;                          // 32
    int*   list   = ibase + 64;                          // 38400
    int*   blockhist = list + NEDGE;                     // 150*26
    int*   blockbase = blockhist + NHB*NREL;             // 150*26
    (void)hb_dead;

    // vg must NOT alias h anymore (k3m reads h while writing vg). Move vg to the
    // dead-hb region instead: 19,660,800 B < vg's 20,971,520 need... so put vg at
    // hb region start minus slack inside xb-dead? xb (incl. qg span) is NOT all dead:
    // qg/kg live there. Use the hb region (19.66MB) + tail of kg region? Simpler:
    // vg goes AFTER ibase (plenty of d_ws left).
    vg = (u16*)((char*)(blockbase + NHB*NREL) + 256);
    vg = (u16*)(((uintptr_t)vg + 255) & ~(uintptr_t)255);

    b_hist<<<NHB, 256, 0, stream>>>(etype, blockhist);
    b_scan<<<1, 64, 0, stream>>>(blockhist, blockbase, cnt, off);
    b_scatter<<<NHB, 256, 0, stream>>>(etype, blockbase, list);

    c_cast8<<<14400, 256, 0, stream>>>((const float4*)x, (uint4*)xb, 3686400);
    c_cast_w<<<2688, 256, 0, stream>>>(wrel, wloop, wq, wrb, wlb, wqb);

    k1m<<<dim3(300, 2), 256, 0, stream>>>((const uint4*)xb, wlb, brel, h);
    k2m<<<dim3(16, 26, 2), 256, 0, stream>>>((const uint4*)xb, wrb, src, dst, cnt, off, list, h);
    // zero only the V-tail fragment chunks (2KB per (b,head), 2MB total) before k3m
    z_tail<<<1024, 128, 0, stream>>>((uint4*)vg);
    k3m<<<600, 256, 0, stream>>>(h, wqb, bq, qg, kg, vg);
    k4_attn<<<BB * NHEADS, 256, 0, stream>>>((const uint4*)qg, (const uint4*)kg, (const uint4*)vg, pooled);
    k5_head<<<BB, 256, 0, stream>>>(pooled, wo, bo, wm, bm, out);
}

// Round 9
// 276.704 us; speedup vs baseline: 1.0301x; 1.0301x over previous
//
#include <hip/hip_runtime.h>
#include <hip/hip_bf16.h>
#include <cstdint>
#include <cstddef>

#define BB 128
#define NN 300
#define EE 300
#define DIN 768
#define DH 256
#define NREL 26
#define NHEADS 8
#define HDIM 32
#define MTOT (BB*NN)    // 38400
#define NEDGE (BB*EE)   // 38400
#define NHB 150         // histogram blocks (150*256 == NEDGE)

typedef __attribute__((ext_vector_type(8))) short bf16x8;
typedef __attribute__((ext_vector_type(4))) float f32x4;
typedef unsigned short u16;
union BU { uint4 u; bf16x8 v; };

__device__ __forceinline__ unsigned int packbf2(float a, float b) {
    unsigned int ua = __float_as_uint(a);
    unsigned int ub = __float_as_uint(b);
    ua = (ua + 0x7FFFu + ((ua >> 16) & 1u)) >> 16;
    ub = (ub + 0x7FFFu + ((ub >> 16) & 1u)) & 0xFFFF0000u;
    return ua | ub;
}
__device__ __forceinline__ u16 packbf1(float a) {
    unsigned int ua = __float_as_uint(a);
    return (u16)((ua + 0x7FFFu + ((ua >> 16) & 1u)) >> 16);
}
__device__ __forceinline__ unsigned cvtpk(float a, float b) {
    union { __hip_bfloat162 h; unsigned u; } cv;
    cv.h = __float22bfloat162_rn(make_float2(a, b));   // v_cvt_pk_bf16_f32
    return cv.u;
}

// ---------------- atomic-free edge bucketing (counting sort by relation) ----------------
__global__ __launch_bounds__(256) void b_hist(const int* __restrict__ etype,
                                              int* __restrict__ blockhist) {
    __shared__ int hist[NREL];
    const int tid = threadIdx.x;
    if (tid < NREL) hist[tid] = 0;
    __syncthreads();
    atomicAdd(&hist[etype[blockIdx.x * 256 + tid]], 1);   // LDS atomic
    __syncthreads();
    if (tid < NREL) blockhist[blockIdx.x * NREL + tid] = hist[tid];
}

__global__ __launch_bounds__(64) void b_scan(const int* __restrict__ blockhist,
                                             int* __restrict__ blockbase,
                                             int* __restrict__ cnt, int* __restrict__ off) {
    __shared__ int tot[NREL];
    const int r = threadIdx.x;
    if (r < NREL) {
        int run = 0;
        for (int b = 0; b < NHB; ++b) {
            blockbase[b * NREL + r] = run;
            run += blockhist[b * NREL + r];
        }
        tot[r] = run;
        cnt[r] = run;
    }
    __syncthreads();
    __shared__ int offs[NREL + 1];
    if (r == 0) {
        int acc = 0;
        for (int q = 0; q < NREL; ++q) { offs[q] = acc; off[q] = acc; acc += tot[q]; }
        offs[NREL] = acc; off[NREL] = acc;
    }
    __syncthreads();
    if (r < NREL) {
        int o = offs[r];
        for (int b = 0; b < NHB; ++b) blockbase[b * NREL + r] += o;
    }
}

__global__ __launch_bounds__(256) void b_scatter(const int* __restrict__ etype,
                                                 const int* __restrict__ blockbase,
                                                 int* __restrict__ list) {
    __shared__ int wavehist[4][NREL];
    __shared__ int waveoff[4][NREL];
    const int tid = threadIdx.x;
    const int w = tid >> 6, l = tid & 63;
    const int i = blockIdx.x * 256 + tid;
    const int r = etype[i];
    unsigned long long mymask = 0ull;
    #pragma unroll
    for (int q = 0; q < NREL; ++q) {
        unsigned long long m = __ballot(r == q);
        if (l == 0) wavehist[w][q] = __popcll(m);
        if (r == q) mymask = m;
    }
    const int myrank = __popcll(mymask & ((1ull << l) - 1ull));
    __syncthreads();
    if (tid < NREL) {
        int acc = 0;
        #pragma unroll
        for (int ww = 0; ww < 4; ++ww) { waveoff[ww][tid] = acc; acc += wavehist[ww][tid]; }
    }
    __syncthreads();
    list[blockbase[blockIdx.x * NREL + r] + waveoff[w][r] + myrank] = i;
}

// ---------------- zero V-tail fragment chunks (jn>=300 slots live only in
// chunks 9 and 19 per (b,head)); k3m then overwrites the valid jn=288..299 part.
__global__ __launch_bounds__(128) void z_tail(uint4* __restrict__ vg4) {
    const int p = blockIdx.x;            // (b*8+hh), 1024 total
    const int tid = threadIdx.x;
    const int f = (tid < 64) ? 9 : 19;
    const int t = tid & 63;
    vg4[(size_t)(p * 20 + f) * 64 + t] = make_uint4(0u, 0u, 0u, 0u);
}

// ---------------- casts ----------------
__global__ __launch_bounds__(256) void c_cast8(const float4* __restrict__ in,
                                               uint4* __restrict__ out, int n8) {
    int i = blockIdx.x * 256 + threadIdx.x;
    if (i < n8) {
        float4 f0 = in[2*i], f1 = in[2*i+1];
        uint4 o;
        o.x = packbf2(f0.x, f0.y); o.y = packbf2(f0.z, f0.w);
        o.z = packbf2(f1.x, f1.y); o.w = packbf2(f1.z, f1.w);
        out[i] = o;
    }
}

// Pack weights into MFMA B-fragment order.
__global__ __launch_bounds__(256) void c_cast_w(
    const float* __restrict__ wrel, const float* __restrict__ wl, const float* __restrict__ wq,
    uint4* __restrict__ wrb, uint4* __restrict__ wlb, uint4* __restrict__ wqb) {
    int t = blockIdx.x * 256 + threadIdx.x;
    int l = t & 63, fid = t >> 6;
    if (fid < NREL*24*16) {
        int r = fid / 384, rem = fid - r * 384;
        int kf = rem >> 4, nt = rem & 15;
        int k0 = 32*kf + 8*(l >> 4), n = 16*nt + (l & 15);
        const float* p = wrel + ((size_t)r*768 + k0) * 256 + n;
        uint4 o;
        o.x = packbf2(p[0], p[256]); o.y = packbf2(p[512], p[768]);
        o.z = packbf2(p[1024], p[1280]); o.w = packbf2(p[1536], p[1792]);
        wrb[t] = o;
    } else if (fid < NREL*24*16 + 384) {
        int f2 = fid - NREL*24*16;
        int kf = f2 >> 4, nt = f2 & 15;
        int k0 = 32*kf + 8*(l >> 4), n = 16*nt + (l & 15);
        const float* p = wl + (size_t)k0 * 256 + n;
        uint4 o;
        o.x = packbf2(p[0], p[256]); o.y = packbf2(p[512], p[768]);
        o.z = packbf2(p[1024], p[1280]); o.w = packbf2(p[1536], p[1792]);
        wlb[f2*64 + l] = o;
    } else {
        int f2 = fid - NREL*24*16 - 384;   // kf*48 + nt
        int kf = f2 / 48, nt = f2 % 48;
        int e = 16*nt + (l & 15), d0 = 32*kf + 8*(l >> 4);
        const float4* p = (const float4*)(wq + (size_t)e * 256 + d0);
        float4 f0 = p[0], f1 = p[1];
        uint4 o;
        o.x = packbf2(f0.x, f0.y); o.y = packbf2(f0.z, f0.w);
        o.z = packbf2(f1.x, f1.y); o.w = packbf2(f1.z, f1.w);
        wqb[f2*64 + l] = o;
    }
}

// ---------------- MFMA GEMM: h = xb @ wlb + b_rel  (M=128 x N=128 tile) ----------------
__global__ __launch_bounds__(256) void k1m(
    const uint4* __restrict__ xb, const uint4* __restrict__ wlb,
    const float* __restrict__ brel, float* __restrict__ h) {
    __shared__ uint4 As[1024];          // 16KB: 128 rows x K64, frag order [kf2][mt8][l64]
    const int tid = threadIdx.x;
    const int m0 = blockIdx.x * 128;
    const int nb = blockIdx.y;
    const int w = tid >> 6, l = tid & 63;
    const int g = l >> 4, q = l & 15;
    int cA[4];
    #pragma unroll
    for (int p = 0; p < 4; ++p) {
        int s = tid + p * 256;
        int fi = s >> 6, l2 = s & 63;
        int kf = fi >> 3, mt = fi & 7;
        int row = m0 + 16*mt + (l2 & 15);
        cA[p] = row * 96 + 4*kf + (l2 >> 4);
    }
    f32x4 acc[8][2];
    #pragma unroll
    for (int a = 0; a < 8; ++a)
        #pragma unroll
        for (int n = 0; n < 2; ++n) acc[a][n] = (f32x4){0.f,0.f,0.f,0.f};

    for (int step = 0; step < 12; ++step) {
        uint4 a0 = xb[cA[0] + step*8];
        uint4 a1 = xb[cA[1] + step*8];
        uint4 a2 = xb[cA[2] + step*8];
        uint4 a3 = xb[cA[3] + step*8];
        BU Bf[2][2];
        #pragma unroll
        for (int kf = 0; kf < 2; ++kf)
            #pragma unroll
            for (int nt = 0; nt < 2; ++nt)
                Bf[kf][nt].u = wlb[((step*2 + kf)*16 + nb*8 + w*2 + nt)*64 + l];
        __syncthreads();
        As[tid] = a0; As[tid + 256] = a1; As[tid + 512] = a2; As[tid + 768] = a3;
        __syncthreads();
        #pragma unroll
        for (int kf = 0; kf < 2; ++kf) {
            #pragma unroll
            for (int mt = 0; mt < 8; ++mt) {
                BU Af; Af.u = As[(kf*8 + mt)*64 + l];
                #pragma unroll
                for (int nt = 0; nt < 2; ++nt)
                    acc[mt][nt] = __builtin_amdgcn_mfma_f32_16x16x32_bf16(Af.v, Bf[kf][nt].v, acc[mt][nt], 0, 0, 0);
            }
        }
    }
    #pragma unroll
    for (int nt = 0; nt < 2; ++nt) {
        int col = nb*128 + w*32 + nt*16 + q;
        float bias = brel[col];
        #pragma unroll
        for (int mt = 0; mt < 8; ++mt)
            #pragma unroll
            for (int i = 0; i < 4; ++i)
                h[(size_t)(m0 + 16*mt + 4*g + i)*256 + col] = acc[mt][nt][i] + bias;
    }
}

// ------- MFMA per-relation msg GEMM + scatter-add (M=128 edges/block) -------
__global__ __launch_bounds__(256) void k2m(
    const uint4* __restrict__ xb, const uint4* __restrict__ wrb,
    const int* __restrict__ src, const int* __restrict__ dst,
    const int* __restrict__ cnt, const int* __restrict__ off,
    const int* __restrict__ list, float* __restrict__ h) {
    __shared__ uint4 As[1024];
    __shared__ int arow_s[128];
    __shared__ int drow_s[128];
    const int r = blockIdx.y;
    const int c_total = cnt[r];
    const int t0 = blockIdx.x * 128;
    if (t0 >= c_total) return;
    const int nb = blockIdx.z;
    const int tid = threadIdx.x;
    if (tid < 128) {
        int e = t0 + tid;
        int ar = 0, dr = -1;
        if (e < c_total) {
            int eid = list[off[r] + e];
            int b = eid / EE;
            ar = b * NN + src[eid];
            dr = b * NN + dst[eid];
        }
        arow_s[tid] = ar; drow_s[tid] = dr;
    }
    __syncthreads();
    const int w = tid >> 6, l = tid & 63;
    const int g = l >> 4, q = l & 15;
    int cA[4];
    #pragma unroll
    for (int p = 0; p < 4; ++p) {
        int s = tid + p * 256;
        int fi = s >> 6, l2 = s & 63;
        int kf = fi >> 3, mt = fi & 7;
        int row = arow_s[16*mt + (l2 & 15)];
        cA[p] = row * 96 + 4*kf + (l2 >> 4);
    }
    const uint4* wb = wrb + (size_t)r * 24*16*64;
    f32x4 acc[8][2];
    #pragma unroll
    for (int a = 0; a < 8; ++a)
        #pragma unroll
        for (int n = 0; n < 2; ++n) acc[a][n] = (f32x4){0.f,0.f,0.f,0.f};

    for (int step = 0; step < 12; ++step) {
        uint4 a0 = xb[cA[0] + step*8];
        uint4 a1 = xb[cA[1] + step*8];
        uint4 a2 = xb[cA[2] + step*8];
        uint4 a3 = xb[cA[3] + step*8];
        BU Bf[2][2];
        #pragma unroll
        for (int kf = 0; kf < 2; ++kf)
            #pragma unroll
            for (int nt = 0; nt < 2; ++nt)
                Bf[kf][nt].u = wb[((step*2 + kf)*16 + nb*8 + w*2 + nt)*64 + l];
        __syncthreads();
        As[tid] = a0; As[tid + 256] = a1; As[tid + 512] = a2; As[tid + 768] = a3;
        __syncthreads();
        #pragma unroll
        for (int kf = 0; kf < 2; ++kf) {
            #pragma unroll
            for (int mt = 0; mt < 8; ++mt) {
                BU Af; Af.u = As[(kf*8 + mt)*64 + l];
                #pragma unroll
                for (int nt = 0; nt < 2; ++nt)
                    acc[mt][nt] = __builtin_amdgcn_mfma_f32_16x16x32_bf16(Af.v, Bf[kf][nt].v, acc[mt][nt], 0, 0, 0);
            }
        }
    }
    #pragma unroll
    for (int mt = 0; mt < 8; ++mt)
        #pragma unroll
        for (int i = 0; i < 4; ++i) {
            int dr = drow_s[16*mt + 4*g + i];
            if (dr >= 0) {
                #pragma unroll
                for (int nt = 0; nt < 2; ++nt)
                    atomicAdd(&h[(size_t)dr*256 + nb*128 + w*32 + nt*16 + q], acc[mt][nt][i]);
            }
        }
}

// ---------------- MFMA qkv = hb @ wqb^T + bias; outputs written DIRECTLY in MFMA
// fragment order per (batch, head):
//  qg/kg [(b*8+hh)*19 + jt]*64 + 16*(d>>3) + (jn&15), u16 slot d&7
//  vg    [(b*8+hh)*20 + (d>>4)*10 + (jn>>5)]*64 + 16*((jn>>3)&3) + (d&15), slot jn&7
__global__ __launch_bounds__(256) void k3m(
    const uint4* __restrict__ hb, const uint4* __restrict__ wqb,
    const float* __restrict__ bq,
    u16* __restrict__ qg, u16* __restrict__ kg, u16* __restrict__ vg) {
    __shared__ uint4 As[512];
    const int tid = threadIdx.x;
    const int m0 = blockIdx.x * 64;
    const int nb = blockIdx.y;           // 6 n-spans of 128
    const int w = tid >> 6, l = tid & 63;
    const int g = l >> 4, q = l & 15;
    int cA[2];
    #pragma unroll
    for (int p = 0; p < 2; ++p) {
        int s = tid + p * 256;
        int fi = s >> 6, l2 = s & 63;
        int kf = fi >> 2, mt = fi & 3;
        int row = m0 + 16*mt + (l2 & 15);
        cA[p] = row * 32 + 4*kf + (l2 >> 4);
    }
    f32x4 acc[4][2];
    #pragma unroll
    for (int a = 0; a < 4; ++a)
        #pragma unroll
        for (int n = 0; n < 2; ++n) acc[a][n] = (f32x4){0.f,0.f,0.f,0.f};

    for (int step = 0; step < 4; ++step) {
        uint4 a0 = hb[cA[0] + step*8];
        uint4 a1 = hb[cA[1] + step*8];
        BU Bf[2][2];
        #pragma unroll
        for (int kf = 0; kf < 2; ++kf)
            #pragma unroll
            for (int nt = 0; nt < 2; ++nt)
                Bf[kf][nt].u = wqb[((step*2 + kf)*48 + nb*8 + w*2 + nt)*64 + l];
        __syncthreads();
        As[tid] = a0; As[tid + 256] = a1;
        __syncthreads();
        #pragma unroll
        for (int kf = 0; kf < 2; ++kf) {
            BU Af[4];
            #pragma unroll
            for (int mt = 0; mt < 4; ++mt) Af[mt].u = As[(kf*4 + mt)*64 + l];
            #pragma unroll
            for (int mt = 0; mt < 4; ++mt)
                #pragma unroll
                for (int nt = 0; nt < 2; ++nt)
                    acc[mt][nt] = __builtin_amdgcn_mfma_f32_16x16x32_bf16(Af[mt].v, Bf[kf][nt].v, acc[mt][nt], 0, 0, 0);
        }
    }
    #pragma unroll
    for (int nt = 0; nt < 2; ++nt) {
        int e = nb*128 + w*32 + nt*16 + q;
        float bias = bq[e];
        int region = e >> 8;              // 0=Q,1=K,2=V
        int hh = (e & 255) >> 5;
        int d  = e & 31;
        u16* outb = (region == 0) ? qg : (region == 1) ? kg : vg;
        #pragma unroll
        for (int mt = 0; mt < 4; ++mt) {
            #pragma unroll
            for (int i = 0; i < 4; ++i) {
                int j = m0 + 16*mt + 4*g + i;
                int b_ = j / 300;
                int jn = j - b_ * 300;
                u16 val = packbf1(acc[mt][nt][i] + bias);
                size_t byte;
                if (region < 2) {
                    int word = ((b_*8 + hh)*19 + (jn >> 4))*64 + 16*(d >> 3) + (jn & 15);
                    byte = (size_t)word*16 + (size_t)(d & 7)*2;
                } else {
                    int word = ((b_*8 + hh)*20 + (d >> 4)*10 + (jn >> 5))*64 + 16*((jn >> 3) & 3) + (d & 15);
                    byte = (size_t)word*16 + (size_t)(jn & 7)*2;
                }
                *(u16*)((char*)outb + byte) = val;
            }
        }
    }
}

// ------- MFMA flash attention, no-max softmax (exp2 direct), batched P-transpose -------
__global__ __launch_bounds__(256) void k4_attn(
    const uint4* __restrict__ qg, const uint4* __restrict__ kg,
    const uint4* __restrict__ vg, float* __restrict__ pooled) {
    __shared__ uint4 kf_s[19*64];
    __shared__ uint4 vt_s[20*64];
    __shared__ __align__(16) u16 pbuf[4][2560];   // 5KB per wave: 5 chunks x 1KB
    __shared__ float pool_lds[4][32];
    const int bh = blockIdx.x;
    const int tid = threadIdx.x;
    for (int s = tid; s < 19*64; s += 256) kf_s[s] = kg[(size_t)bh*19*64 + s];
    for (int s = tid; s < 20*64; s += 256) vt_s[s] = vg[(size_t)bh*20*64 + s];
    __syncthreads();

    const int w = tid >> 6, l = tid & 63;
    const int g = l >> 4, q = l & 15;
    char* pwbase = (char*)pbuf[w] + 256*(g >> 1) + 16*q + 8*(g & 1);
    const uint4* prd = (const uint4*)pbuf[w];

    const float c1 = 0.17677669529663687f * 1.4426950408889634f;  // (1/sqrt(32))*log2(e)
    float pool[8] = {0.f,0.f,0.f,0.f,0.f,0.f,0.f,0.f};

    for (int qt = w; qt < 19; qt += 4) {
        const int qrow = qt * 16 + q;
        BU uq; uq.u = qg[(size_t)(bh*19 + qt)*64 + l];
        float lsum = 0.f;
        f32x4 ctx0 = {0.f,0.f,0.f,0.f}, ctx1 = {0.f,0.f,0.f,0.f};

        #pragma unroll
        for (int half = 0; half < 2; ++half) {
            #pragma unroll
            for (int jj = 0; jj < 10; ++jj) {
                const int jt = half*10 + jj;
                uint2 pk = make_uint2(0u, 0u);
                if (jt < 19) {
                    BU uk; uk.u = kf_s[jt*64 + l];
                    f32x4 z = {0.f,0.f,0.f,0.f};
                    f32x4 s4 = __builtin_amdgcn_mfma_f32_16x16x32_bf16(uk.v, uq.v, z, 0, 0, 0);
                    float p0 = exp2f(s4[0]*c1);
                    float p1 = exp2f(s4[1]*c1);
                    float p2 = exp2f(s4[2]*c1);
                    float p3 = exp2f(s4[3]*c1);
                    if (jt == 18 && g == 3) { p0 = 0.f; p1 = 0.f; p2 = 0.f; p3 = 0.f; }
                    lsum += (p0 + p1) + (p2 + p3);
                    pk.x = cvtpk(p0, p1);
                    pk.y = cvtpk(p2, p3);
                }
                *(uint2*)(pwbase + 512*jj) = pk;
            }
            #pragma unroll
            for (int cc = 0; cc < 5; ++cc) {
                const int cg = half*5 + cc;
                BU up;  up.u  = prd[cc*64 + l];
                BU uv0; uv0.u = vt_s[cg*64 + l];
                BU uv1; uv1.u = vt_s[(10 + cg)*64 + l];
                ctx0 = __builtin_amdgcn_mfma_f32_16x16x32_bf16(uv0.v, up.v, ctx0, 0, 0, 0);
                ctx1 = __builtin_amdgcn_mfma_f32_16x16x32_bf16(uv1.v, up.v, ctx1, 0, 0, 0);
            }
        }
        lsum += __shfl_xor(lsum, 16);
        lsum += __shfl_xor(lsum, 32);
        if (qrow < NN) {
            float inv = 1.0f / lsum;
            pool[0] += ctx0[0] * inv; pool[1] += ctx0[1] * inv;
            pool[2] += ctx0[2] * inv; pool[3] += ctx0[3] * inv;
            pool[4] += ctx1[0] * inv; pool[5] += ctx1[1] * inv;
            pool[6] += ctx1[2] * inv; pool[7] += ctx1[3] * inv;
        }
    }

    #pragma unroll
    for (int i = 0; i < 8; ++i) {
        float v = pool[i];
        v += __shfl_xor(v, 1); v += __shfl_xor(v, 2);
        v += __shfl_xor(v, 4); v += __shfl_xor(v, 8);
        pool[i] = v;
    }
    if (q == 0) {
        #pragma unroll
        for (int dt = 0; dt < 2; ++dt)
            #pragma unroll
            for (int i = 0; i < 4; ++i)
                pool_lds[w][dt * 16 + 4 * g + i] = pool[dt * 4 + i];
    }
    __syncthreads();
    if (tid < 32) {
        int b = bh >> 3, hh = bh & 7;
        float s = pool_lds[0][tid] + pool_lds[1][tid] + pool_lds[2][tid] + pool_lds[3][tid];
        pooled[(size_t)b * DH + hh * HDIM + tid] = s * (1.0f / 300.0f);
    }
}

// ------- out = ((pooled @ out_proj^T + bo) @ mlp^T + bm) -------
__global__ __launch_bounds__(256) void k5_head(
    const float* __restrict__ pooled, const float* __restrict__ wo, const float* __restrict__ bo,
    const float* __restrict__ wm, const float* __restrict__ bm, float* __restrict__ out) {
    __shared__ float pc[DH];
    __shared__ float t1[DH];
    const int b = blockIdx.x, tid = threadIdx.x;
    pc[tid] = pooled[(size_t)b * DH + tid];
    __syncthreads();
    float acc = bo[tid];
    for (int d = 0; d < DH; ++d) acc += pc[d] * wo[(size_t)tid * DH + d];
    t1[tid] = acc;
    __syncthreads();
    float acc2 = bm[tid];
    for (int e2 = 0; e2 < DH; ++e2) acc2 += t1[e2] * wm[(size_t)tid * DH + e2];
    out[(size_t)b * DH + tid] = acc2;
}

extern "C" void kernel_launch(void* const* d_in, const int* in_sizes, int n_in,
                              void* d_out, int out_size, void* d_ws, size_t ws_size,
                              hipStream_t stream) {
    (void)in_sizes; (void)n_in; (void)out_size; (void)ws_size;
    const float* x     = (const float*)d_in[0];
    const int*   src   = (const int*)d_in[1];
    const int*   dst   = (const int*)d_in[2];
    const int*   etype = (const int*)d_in[3];
    const float* wrel  = (const float*)d_in[4];
    const float* wloop = (const float*)d_in[5];
    const float* brel  = (const float*)d_in[6];
    const float* wq    = (const float*)d_in[7];
    const float* bq    = (const float*)d_in[8];
    const float* wo    = (const float*)d_in[9];
    const float* bo    = (const float*)d_in[10];
    const float* wm    = (const float*)d_in[11];
    const float* bm    = (const float*)d_in[12];
    float* out = (float*)d_out;

    char* W = (char*)d_ws;
    float* h      = (float*)W;                          // 39,321,600 B
    u16*   xb     = (u16*)(W + 39321600ull);            // 58,982,400 B (dead after k2m)
    u16*   qg     = xb;                                 // 19,922,944 B (k3m writes after xb dead)
    u16*   kg     = (u16*)(W + 39321600ull + 19922944ull);  // 19,922,944 B
    u16*   hb     = (u16*)(W + 39321600ull + 58982400ull);  // 19,660,800 B
    uint4* wrb    = (uint4*)(W + 39321600ull + 58982400ull + 19660800ull);  // 10,223,616
    uint4* wlb    = (uint4*)((char*)wrb + 10223616ull);
    uint4* wqb    = (uint4*)((char*)wlb + 393216ull);
    float* pooled = (float*)((char*)wqb + 393216ull);
    int*   ibase  = (int*)((char*)pooled + 131072ull);
    int*   cnt    = ibase;                               // 32
    int*   off    = ibase + 32;                          // 32
    int*   list   = ibase + 64;                          // 38400
    int*   blockhist = list + NEDGE;                     // 150*26
    int*   blockbase = blockhist + NHB*NREL;             // 150*26
    // vg in its own region past the index data (R8-verified within ws_size)
    u16*   vg = (u16*)((char*)(blockbase + NHB*NREL) + 256);
    vg = (u16*)(((uintptr_t)vg + 255) & ~(uintptr_t)255);

    b_hist<<<NHB, 256, 0, stream>>>(etype, blockhist);
    b_scan<<<1, 64, 0, stream>>>(blockhist, blockbase, cnt, off);
    b_scatter<<<NHB, 256, 0, stream>>>(etype, blockbase, list);

    c_cast8<<<14400, 256, 0, stream>>>((const float4*)x, (uint4*)xb, 3686400);
    c_cast_w<<<2688, 256, 0, stream>>>(wrel, wloop, wq, wrb, wlb, wqb);

    k1m<<<dim3(300, 2), 256, 0, stream>>>((const uint4*)xb, wlb, brel, h);
    k2m<<<dim3(16, 26, 2), 256, 0, stream>>>((const uint4*)xb, wrb, src, dst, cnt, off, list, h);
    c_cast8<<<4800, 256, 0, stream>>>((const float4*)h, (uint4*)hb, 1228800);
    // zero only the V-tail fragment chunks (2KB per (b,head), 2MB total) before k3m
    z_tail<<<1024, 128, 0, stream>>>((uint4*)vg);
    k3m<<<dim3(600, 6), 256, 0, stream>>>((const uint4*)hb, wqb, bq, qg, kg, vg);
    k4_attn<<<BB * NHEADS, 256, 0, stream>>>((const uint4*)qg, (const uint4*)kg, (const uint4*)vg, pooled);
    k5_head<<<BB, 256, 0, stream>>>(pooled, wo, bo, wm, bm, out);
}

// Round 10
// 276.208 us; speedup vs baseline: 1.0319x; 1.0018x over previous
//
#include <hip/hip_runtime.h>
#include <hip/hip_bf16.h>
#include <cstdint>
#include <cstddef>

#define BB 128
#define NN 300
#define EE 300
#define DIN 768
#define DH 256
#define NREL 26
#define NHEADS 8
#define HDIM 32
#define MTOT (BB*NN)    // 38400
#define NEDGE (BB*EE)   // 38400
#define NHB 150         // histogram blocks (150*256 == NEDGE)

typedef __attribute__((ext_vector_type(8))) short bf16x8;
typedef __attribute__((ext_vector_type(4))) float f32x4;
typedef unsigned short u16;
union BU { uint4 u; bf16x8 v; };

__device__ __forceinline__ unsigned int packbf2(float a, float b) {
    unsigned int ua = __float_as_uint(a);
    unsigned int ub = __float_as_uint(b);
    ua = (ua + 0x7FFFu + ((ua >> 16) & 1u)) >> 16;
    ub = (ub + 0x7FFFu + ((ub >> 16) & 1u)) & 0xFFFF0000u;
    return ua | ub;
}
__device__ __forceinline__ u16 packbf1(float a) {
    unsigned int ua = __float_as_uint(a);
    return (u16)((ua + 0x7FFFu + ((ua >> 16) & 1u)) >> 16);
}
__device__ __forceinline__ unsigned cvtpk(float a, float b) {
    union { __hip_bfloat162 h; unsigned u; } cv;
    cv.h = __float22bfloat162_rn(make_float2(a, b));   // v_cvt_pk_bf16_f32
    return cv.u;
}

// ---------------- atomic-free edge bucketing (counting sort by relation) ----------------
__global__ __launch_bounds__(256) void b_hist(const int* __restrict__ etype,
                                              int* __restrict__ blockhist) {
    __shared__ int hist[NREL];
    const int tid = threadIdx.x;
    if (tid < NREL) hist[tid] = 0;
    __syncthreads();
    atomicAdd(&hist[etype[blockIdx.x * 256 + tid]], 1);   // LDS atomic
    __syncthreads();
    if (tid < NREL) blockhist[blockIdx.x * NREL + tid] = hist[tid];
}

__global__ __launch_bounds__(64) void b_scan(const int* __restrict__ blockhist,
                                             int* __restrict__ blockbase,
                                             int* __restrict__ cnt, int* __restrict__ off) {
    __shared__ int tot[NREL];
    const int r = threadIdx.x;
    if (r < NREL) {
        int run = 0;
        for (int b = 0; b < NHB; ++b) {
            blockbase[b * NREL + r] = run;
            run += blockhist[b * NREL + r];
        }
        tot[r] = run;
        cnt[r] = run;
    }
    __syncthreads();
    __shared__ int offs[NREL + 1];
    if (r == 0) {
        int acc = 0;
        for (int q = 0; q < NREL; ++q) { offs[q] = acc; off[q] = acc; acc += tot[q]; }
        offs[NREL] = acc; off[NREL] = acc;
    }
    __syncthreads();
    if (r < NREL) {
        int o = offs[r];
        for (int b = 0; b < NHB; ++b) blockbase[b * NREL + r] += o;
    }
}

__global__ __launch_bounds__(256) void b_scatter(const int* __restrict__ etype,
                                                 const int* __restrict__ blockbase,
                                                 int* __restrict__ list) {
    __shared__ int wavehist[4][NREL];
    __shared__ int waveoff[4][NREL];
    const int tid = threadIdx.x;
    const int w = tid >> 6, l = tid & 63;
    const int i = blockIdx.x * 256 + tid;
    const int r = etype[i];
    unsigned long long mymask = 0ull;
    #pragma unroll
    for (int q = 0; q < NREL; ++q) {
        unsigned long long m = __ballot(r == q);
        if (l == 0) wavehist[w][q] = __popcll(m);
        if (r == q) mymask = m;
    }
    const int myrank = __popcll(mymask & ((1ull << l) - 1ull));
    __syncthreads();
    if (tid < NREL) {
        int acc = 0;
        #pragma unroll
        for (int ww = 0; ww < 4; ++ww) { waveoff[ww][tid] = acc; acc += wavehist[ww][tid]; }
    }
    __syncthreads();
    list[blockbase[blockIdx.x * NREL + r] + waveoff[w][r] + myrank] = i;
}

// ---------------- casts (+ folded V-tail zeroing in trailing 8 blocks) ----------------
__global__ __launch_bounds__(256) void c_cast8(const float4* __restrict__ in,
                                               uint4* __restrict__ out, int n8) {
    int i = blockIdx.x * 256 + threadIdx.x;
    if (i < n8) {
        float4 f0 = in[2*i], f1 = in[2*i+1];
        uint4 o;
        o.x = packbf2(f0.x, f0.y); o.y = packbf2(f0.z, f0.w);
        o.z = packbf2(f1.x, f1.y); o.w = packbf2(f1.z, f1.w);
        out[i] = o;
    }
}

// Pack weights into MFMA B-fragment order. Blocks >= 2688 zero the V-tail
// fragment chunks (chunks 9/19 per (b,head): jn>=300 slots; k3m overwrites valid part).
__global__ __launch_bounds__(256) void c_cast_w(
    const float* __restrict__ wrel, const float* __restrict__ wl, const float* __restrict__ wq,
    uint4* __restrict__ wrb, uint4* __restrict__ wlb, uint4* __restrict__ wqb,
    uint4* __restrict__ vg4) {
    if (blockIdx.x >= 2688) {
        int t2 = (blockIdx.x - 2688) * 256 + threadIdx.x;   // 0..2047
        #pragma unroll
        for (int j = 0; j < 64; ++j) {
            int m = t2 + j * 2048;            // 0..131071
            int pf = m >> 6, t = m & 63;
            int p = pf >> 1, f = (pf & 1) ? 19 : 9;
            vg4[(size_t)(p * 20 + f) * 64 + t] = make_uint4(0u, 0u, 0u, 0u);
        }
        return;
    }
    int t = blockIdx.x * 256 + threadIdx.x;
    int l = t & 63, fid = t >> 6;
    if (fid < NREL*24*16) {
        int r = fid / 384, rem = fid - r * 384;
        int kf = rem >> 4, nt = rem & 15;
        int k0 = 32*kf + 8*(l >> 4), n = 16*nt + (l & 15);
        const float* p = wrel + ((size_t)r*768 + k0) * 256 + n;
        uint4 o;
        o.x = packbf2(p[0], p[256]); o.y = packbf2(p[512], p[768]);
        o.z = packbf2(p[1024], p[1280]); o.w = packbf2(p[1536], p[1792]);
        wrb[t] = o;
    } else if (fid < NREL*24*16 + 384) {
        int f2 = fid - NREL*24*16;
        int kf = f2 >> 4, nt = f2 & 15;
        int k0 = 32*kf + 8*(l >> 4), n = 16*nt + (l & 15);
        const float* p = wl + (size_t)k0 * 256 + n;
        uint4 o;
        o.x = packbf2(p[0], p[256]); o.y = packbf2(p[512], p[768]);
        o.z = packbf2(p[1024], p[1280]); o.w = packbf2(p[1536], p[1792]);
        wlb[f2*64 + l] = o;
    } else {
        int f2 = fid - NREL*24*16 - 384;   // kf*48 + nt
        int kf = f2 / 48, nt = f2 % 48;
        int e = 16*nt + (l & 15), d0 = 32*kf + 8*(l >> 4);
        const float4* p = (const float4*)(wq + (size_t)e * 256 + d0);
        float4 f0 = p[0], f1 = p[1];
        uint4 o;
        o.x = packbf2(f0.x, f0.y); o.y = packbf2(f0.z, f0.w);
        o.z = packbf2(f1.x, f1.y); o.w = packbf2(f1.z, f1.w);
        wqb[f2*64 + l] = o;
    }
}

// ---------------- MFMA GEMM: h = xb @ wlb + b_rel  (64x128 tile, R7 shape) ----------------
__global__ __launch_bounds__(256) void k1m(
    const uint4* __restrict__ xb, const uint4* __restrict__ wlb,
    const float* __restrict__ brel, float* __restrict__ h) {
    __shared__ uint4 As[512];
    const int tid = threadIdx.x;
    const int m0 = blockIdx.x * 64;
    const int nb = blockIdx.y;
    const int w = tid >> 6, l = tid & 63;
    const int g = l >> 4, q = l & 15;
    int cA[2];
    #pragma unroll
    for (int p = 0; p < 2; ++p) {
        int s = tid + p * 256;
        int fi = s >> 6, l2 = s & 63;
        int kf = fi >> 2, mt = fi & 3;
        int row = m0 + 16*mt + (l2 & 15);
        cA[p] = row * 96 + 4*kf + (l2 >> 4);
    }
    f32x4 acc[4][2];
    #pragma unroll
    for (int a = 0; a < 4; ++a)
        #pragma unroll
        for (int n = 0; n < 2; ++n) acc[a][n] = (f32x4){0.f,0.f,0.f,0.f};

    for (int step = 0; step < 12; ++step) {
        uint4 a0 = xb[cA[0] + step*8];
        uint4 a1 = xb[cA[1] + step*8];
        BU Bf[2][2];
        #pragma unroll
        for (int kf = 0; kf < 2; ++kf)
            #pragma unroll
            for (int nt = 0; nt < 2; ++nt)
                Bf[kf][nt].u = wlb[((step*2 + kf)*16 + nb*8 + w*2 + nt)*64 + l];
        __syncthreads();
        As[tid] = a0; As[tid + 256] = a1;
        __syncthreads();
        #pragma unroll
        for (int kf = 0; kf < 2; ++kf) {
            BU Af[4];
            #pragma unroll
            for (int mt = 0; mt < 4; ++mt) Af[mt].u = As[(kf*4 + mt)*64 + l];
            #pragma unroll
            for (int mt = 0; mt < 4; ++mt)
                #pragma unroll
                for (int nt = 0; nt < 2; ++nt)
                    acc[mt][nt] = __builtin_amdgcn_mfma_f32_16x16x32_bf16(Af[mt].v, Bf[kf][nt].v, acc[mt][nt], 0, 0, 0);
        }
    }
    #pragma unroll
    for (int nt = 0; nt < 2; ++nt) {
        int col = nb*128 + w*32 + nt*16 + q;
        float bias = brel[col];
        #pragma unroll
        for (int mt = 0; mt < 4; ++mt)
            #pragma unroll
            for (int i = 0; i < 4; ++i)
                h[(size_t)(m0 + 16*mt + 4*g + i)*256 + col] = acc[mt][nt][i] + bias;
    }
}

// ------- MFMA per-relation msg GEMM + scatter-add (M=64 edges, FULL N=256 per block) -------
__global__ __launch_bounds__(256) void k2m(
    const uint4* __restrict__ xb, const uint4* __restrict__ wrb,
    const int* __restrict__ src, const int* __restrict__ dst,
    const int* __restrict__ cnt, const int* __restrict__ off,
    const int* __restrict__ list, float* __restrict__ h) {
    __shared__ uint4 As[512];
    __shared__ int arow_s[64];
    __shared__ int drow_s[64];
    const int r = blockIdx.y;
    const int c_total = cnt[r];
    const int t0 = blockIdx.x * 64;
    if (t0 >= c_total) return;
    const int tid = threadIdx.x;
    if (tid < 64) {
        int e = t0 + tid;
        int ar = 0, dr = -1;
        if (e < c_total) {
            int eid = list[off[r] + e];
            int b = eid / EE;
            ar = b * NN + src[eid];
            dr = b * NN + dst[eid];
        }
        arow_s[tid] = ar; drow_s[tid] = dr;
    }
    __syncthreads();
    const int w = tid >> 6, l = tid & 63;
    const int g = l >> 4, q = l & 15;
    int cA[2];
    #pragma unroll
    for (int p = 0; p < 2; ++p) {
        int s = tid + p * 256;
        int fi = s >> 6, l2 = s & 63;
        int kf = fi >> 2, mt = fi & 3;
        int row = arow_s[16*mt + (l2 & 15)];
        cA[p] = row * 96 + 4*kf + (l2 >> 4);
    }
    const uint4* wb = wrb + (size_t)r * 24*16*64;
    f32x4 acc[4][4];
    #pragma unroll
    for (int a = 0; a < 4; ++a)
        #pragma unroll
        for (int n = 0; n < 4; ++n) acc[a][n] = (f32x4){0.f,0.f,0.f,0.f};

    for (int step = 0; step < 12; ++step) {
        uint4 a0 = xb[cA[0] + step*8];
        uint4 a1 = xb[cA[1] + step*8];
        BU Bf[2][4];
        #pragma unroll
        for (int kf = 0; kf < 2; ++kf)
            #pragma unroll
            for (int nt = 0; nt < 4; ++nt)
                Bf[kf][nt].u = wb[((step*2 + kf)*16 + w*4 + nt)*64 + l];
        __syncthreads();
        As[tid] = a0; As[tid + 256] = a1;
        __syncthreads();
        #pragma unroll
        for (int kf = 0; kf < 2; ++kf) {
            BU Af[4];
            #pragma unroll
            for (int mt = 0; mt < 4; ++mt) Af[mt].u = As[(kf*4 + mt)*64 + l];
            #pragma unroll
            for (int mt = 0; mt < 4; ++mt)
                #pragma unroll
                for (int nt = 0; nt < 4; ++nt)
                    acc[mt][nt] = __builtin_amdgcn_mfma_f32_16x16x32_bf16(Af[mt].v, Bf[kf][nt].v, acc[mt][nt], 0, 0, 0);
        }
    }
    #pragma unroll
    for (int mt = 0; mt < 4; ++mt)
        #pragma unroll
        for (int i = 0; i < 4; ++i) {
            int dr = drow_s[16*mt + 4*g + i];
            if (dr >= 0) {
                #pragma unroll
                for (int nt = 0; nt < 4; ++nt)
                    atomicAdd(&h[(size_t)dr*256 + w*64 + nt*16 + q], acc[mt][nt][i]);
            }
        }
}

// ---------------- MFMA qkv = hb @ wqb^T + bias; outputs written DIRECTLY in MFMA
// fragment order per (batch, head) -- R7 shape, grid (600,6).
__global__ __launch_bounds__(256) void k3m(
    const uint4* __restrict__ hb, const uint4* __restrict__ wqb,
    const float* __restrict__ bq,
    u16* __restrict__ qg, u16* __restrict__ kg, u16* __restrict__ vg) {
    __shared__ uint4 As[512];
    const int tid = threadIdx.x;
    const int m0 = blockIdx.x * 64;
    const int nb = blockIdx.y;           // 6 n-spans of 128
    const int w = tid >> 6, l = tid & 63;
    const int g = l >> 4, q = l & 15;
    int cA[2];
    #pragma unroll
    for (int p = 0; p < 2; ++p) {
        int s = tid + p * 256;
        int fi = s >> 6, l2 = s & 63;
        int kf = fi >> 2, mt = fi & 3;
        int row = m0 + 16*mt + (l2 & 15);
        cA[p] = row * 32 + 4*kf + (l2 >> 4);
    }
    f32x4 acc[4][2];
    #pragma unroll
    for (int a = 0; a < 4; ++a)
        #pragma unroll
        for (int n = 0; n < 2; ++n) acc[a][n] = (f32x4){0.f,0.f,0.f,0.f};

    for (int step = 0; step < 4; ++step) {
        uint4 a0 = hb[cA[0] + step*8];
        uint4 a1 = hb[cA[1] + step*8];
        BU Bf[2][2];
        #pragma unroll
        for (int kf = 0; kf < 2; ++kf)
            #pragma unroll
            for (int nt = 0; nt < 2; ++nt)
                Bf[kf][nt].u = wqb[((step*2 + kf)*48 + nb*8 + w*2 + nt)*64 + l];
        __syncthreads();
        As[tid] = a0; As[tid + 256] = a1;
        __syncthreads();
        #pragma unroll
        for (int kf = 0; kf < 2; ++kf) {
            BU Af[4];
            #pragma unroll
            for (int mt = 0; mt < 4; ++mt) Af[mt].u = As[(kf*4 + mt)*64 + l];
            #pragma unroll
            for (int mt = 0; mt < 4; ++mt)
                #pragma unroll
                for (int nt = 0; nt < 2; ++nt)
                    acc[mt][nt] = __builtin_amdgcn_mfma_f32_16x16x32_bf16(Af[mt].v, Bf[kf][nt].v, acc[mt][nt], 0, 0, 0);
        }
    }
    #pragma unroll
    for (int nt = 0; nt < 2; ++nt) {
        int e = nb*128 + w*32 + nt*16 + q;
        float bias = bq[e];
        int region = e >> 8;              // 0=Q,1=K,2=V
        int hh = (e & 255) >> 5;
        int d  = e & 31;
        u16* outb = (region == 0) ? qg : (region == 1) ? kg : vg;
        #pragma unroll
        for (int mt = 0; mt < 4; ++mt) {
            #pragma unroll
            for (int i = 0; i < 4; ++i) {
                int j = m0 + 16*mt + 4*g + i;
                int b_ = j / 300;
                int jn = j - b_ * 300;
                u16 val = packbf1(acc[mt][nt][i] + bias);
                size_t byte;
                if (region < 2) {
                    int word = ((b_*8 + hh)*19 + (jn >> 4))*64 + 16*(d >> 3) + (jn & 15);
                    byte = (size_t)word*16 + (size_t)(d & 7)*2;
                } else {
                    int word = ((b_*8 + hh)*20 + (d >> 4)*10 + (jn >> 5))*64 + 16*((jn >> 3) & 3) + (d & 15);
                    byte = (size_t)word*16 + (size_t)(jn & 7)*2;
                }
                *(u16*)((char*)outb + byte) = val;
            }
        }
    }
}

// ------- MFMA flash attention, no-max softmax (exp2 direct), batched P-transpose -------
__global__ __launch_bounds__(256) void k4_attn(
    const uint4* __restrict__ qg, const uint4* __restrict__ kg,
    const uint4* __restrict__ vg, float* __restrict__ pooled) {
    __shared__ uint4 kf_s[19*64];
    __shared__ uint4 vt_s[20*64];
    __shared__ __align__(16) u16 pbuf[4][2560];   // 5KB per wave: 5 chunks x 1KB
    __shared__ float pool_lds[4][32];
    const int bh = blockIdx.x;
    const int tid = threadIdx.x;
    for (int s = tid; s < 19*64; s += 256) kf_s[s] = kg[(size_t)bh*19*64 + s];
    for (int s = tid; s < 20*64; s += 256) vt_s[s] = vg[(size_t)bh*20*64 + s];
    __syncthreads();

    const int w = tid >> 6, l = tid & 63;
    const int g = l >> 4, q = l & 15;
    char* pwbase = (char*)pbuf[w] + 256*(g >> 1) + 16*q + 8*(g & 1);
    const uint4* prd = (const uint4*)pbuf[w];

    const float c1 = 0.17677669529663687f * 1.4426950408889634f;  // (1/sqrt(32))*log2(e)
    float pool[8] = {0.f,0.f,0.f,0.f,0.f,0.f,0.f,0.f};

    for (int qt = w; qt < 19; qt += 4) {
        const int qrow = qt * 16 + q;
        BU uq; uq.u = qg[(size_t)(bh*19 + qt)*64 + l];
        float lsum = 0.f;
        f32x4 ctx0 = {0.f,0.f,0.f,0.f}, ctx1 = {0.f,0.f,0.f,0.f};

        #pragma unroll
        for (int half = 0; half < 2; ++half) {
            #pragma unroll
            for (int jj = 0; jj < 10; ++jj) {
                const int jt = half*10 + jj;
                uint2 pk = make_uint2(0u, 0u);
                if (jt < 19) {
                    BU uk; uk.u = kf_s[jt*64 + l];
                    f32x4 z = {0.f,0.f,0.f,0.f};
                    f32x4 s4 = __builtin_amdgcn_mfma_f32_16x16x32_bf16(uk.v, uq.v, z, 0, 0, 0);
                    float p0 = exp2f(s4[0]*c1);
                    float p1 = exp2f(s4[1]*c1);
                    float p2 = exp2f(s4[2]*c1);
                    float p3 = exp2f(s4[3]*c1);
                    if (jt == 18 && g == 3) { p0 = 0.f; p1 = 0.f; p2 = 0.f; p3 = 0.f; }
                    lsum += (p0 + p1) + (p2 + p3);
                    pk.x = cvtpk(p0, p1);
                    pk.y = cvtpk(p2, p3);
                }
                *(uint2*)(pwbase + 512*jj) = pk;
            }
            #pragma unroll
            for (int cc = 0; cc < 5; ++cc) {
                const int cg = half*5 + cc;
                BU up;  up.u  = prd[cc*64 + l];
                BU uv0; uv0.u = vt_s[cg*64 + l];
                BU uv1; uv1.u = vt_s[(10 + cg)*64 + l];
                ctx0 = __builtin_amdgcn_mfma_f32_16x16x32_bf16(uv0.v, up.v, ctx0, 0, 0, 0);
                ctx1 = __builtin_amdgcn_mfma_f32_16x16x32_bf16(uv1.v, up.v, ctx1, 0, 0, 0);
            }
        }
        lsum += __shfl_xor(lsum, 16);
        lsum += __shfl_xor(lsum, 32);
        if (qrow < NN) {
            float inv = 1.0f / lsum;
            pool[0] += ctx0[0] * inv; pool[1] += ctx0[1] * inv;
            pool[2] += ctx0[2] * inv; pool[3] += ctx0[3] * inv;
            pool[4] += ctx1[0] * inv; pool[5] += ctx1[1] * inv;
            pool[6] += ctx1[2] * inv; pool[7] += ctx1[3] * inv;
        }
    }

    #pragma unroll
    for (int i = 0; i < 8; ++i) {
        float v = pool[i];
        v += __shfl_xor(v, 1); v += __shfl_xor(v, 2);
        v += __shfl_xor(v, 4); v += __shfl_xor(v, 8);
        pool[i] = v;
    }
    if (q == 0) {
        #pragma unroll
        for (int dt = 0; dt < 2; ++dt)
            #pragma unroll
            for (int i = 0; i < 4; ++i)
                pool_lds[w][dt * 16 + 4 * g + i] = pool[dt * 4 + i];
    }
    __syncthreads();
    if (tid < 32) {
        int b = bh >> 3, hh = bh & 7;
        float s = pool_lds[0][tid] + pool_lds[1][tid] + pool_lds[2][tid] + pool_lds[3][tid];
        pooled[(size_t)b * DH + hh * HDIM + tid] = s * (1.0f / 300.0f);
    }
}

// ------- out = ((pooled @ out_proj^T + bo) @ mlp^T + bm) -------
__global__ __launch_bounds__(256) void k5_head(
    const float* __restrict__ pooled, const float* __restrict__ wo, const float* __restrict__ bo,
    const float* __restrict__ wm, const float* __restrict__ bm, float* __restrict__ out) {
    __shared__ float pc[DH];
    __shared__ float t1[DH];
    const int b = blockIdx.x, tid = threadIdx.x;
    pc[tid] = pooled[(size_t)b * DH + tid];
    __syncthreads();
    float acc = bo[tid];
    for (int d = 0; d < DH; ++d) acc += pc[d] * wo[(size_t)tid * DH + d];
    t1[tid] = acc;
    __syncthreads();
    float acc2 = bm[tid];
    for (int e2 = 0; e2 < DH; ++e2) acc2 += t1[e2] * wm[(size_t)tid * DH + e2];
    out[(size_t)b * DH + tid] = acc2;
}

extern "C" void kernel_launch(void* const* d_in, const int* in_sizes, int n_in,
                              void* d_out, int out_size, void* d_ws, size_t ws_size,
                              hipStream_t stream) {
    (void)in_sizes; (void)n_in; (void)out_size; (void)ws_size;
    const float* x     = (const float*)d_in[0];
    const int*   src   = (const int*)d_in[1];
    const int*   dst   = (const int*)d_in[2];
    const int*   etype = (const int*)d_in[3];
    const float* wrel  = (const float*)d_in[4];
    const float* wloop = (const float*)d_in[5];
    const float* brel  = (const float*)d_in[6];
    const float* wq    = (const float*)d_in[7];
    const float* bq    = (const float*)d_in[8];
    const float* wo    = (const float*)d_in[9];
    const float* bo    = (const float*)d_in[10];
    const float* wm    = (const float*)d_in[11];
    const float* bm    = (const float*)d_in[12];
    float* out = (float*)d_out;

    char* W = (char*)d_ws;
    float* h      = (float*)W;                          // 39,321,600 B
    u16*   xb     = (u16*)(W + 39321600ull);            // 58,982,400 B (dead after k2m)
    u16*   qg     = xb;                                 // 19,922,944 B (k3m writes after xb dead)
    u16*   kg     = (u16*)(W + 39321600ull + 19922944ull);  // 19,922,944 B
    u16*   hb     = (u16*)(W + 39321600ull + 58982400ull);  // 19,660,800 B
    uint4* wrb    = (uint4*)(W + 39321600ull + 58982400ull + 19660800ull);  // 10,223,616
    uint4* wlb    = (uint4*)((char*)wrb + 10223616ull);
    uint4* wqb    = (uint4*)((char*)wlb + 393216ull);
    float* pooled = (float*)((char*)wqb + 393216ull);
    int*   ibase  = (int*)((char*)pooled + 131072ull);
    int*   cnt    = ibase;                               // 32
    int*   off    = ibase + 32;                          // 32
    int*   list   = ibase + 64;                          // 38400
    int*   blockhist = list + NEDGE;                     // 150*26
    int*   blockbase = blockhist + NHB*NREL;             // 150*26
    // vg in its own region past the index data (R8-verified within ws_size)
    u16*   vg = (u16*)((char*)(blockbase + NHB*NREL) + 256);
    vg = (u16*)(((uintptr_t)vg + 255) & ~(uintptr_t)255);

    b_hist<<<NHB, 256, 0, stream>>>(etype, blockhist);
    b_scan<<<1, 64, 0, stream>>>(blockhist, blockbase, cnt, off);
    b_scatter<<<NHB, 256, 0, stream>>>(etype, blockbase, list);

    c_cast8<<<14400, 256, 0, stream>>>((const float4*)x, (uint4*)xb, 3686400);
    c_cast_w<<<2696, 256, 0, stream>>>(wrel, wloop, wq, wrb, wlb, wqb, (uint4*)vg);

    k1m<<<dim3(600, 2), 256, 0, stream>>>((const uint4*)xb, wlb, brel, h);
    k2m<<<dim3(32, 26), 256, 0, stream>>>((const uint4*)xb, wrb, src, dst, cnt, off, list, h);
    c_cast8<<<4800, 256, 0, stream>>>((const float4*)h, (uint4*)hb, 1228800);
    k3m<<<dim3(600, 6), 256, 0, stream>>>((const uint4*)hb, wqb, bq, qg, kg, vg);
    k4_attn<<<BB * NHEADS, 256, 0, stream>>>((const uint4*)qg, (const uint4*)kg, (const uint4*)vg, pooled);
    k5_head<<<BB, 256, 0, stream>>>(pooled, wo, bo, wm, bm, out);
}

// Round 11
// 268.304 us; speedup vs baseline: 1.0623x; 1.0295x over previous
//
#include <hip/hip_runtime.h>
#include <hip/hip_bf16.h>
#include <cstdint>
#include <cstddef>

#define BB 128
#define NN 300
#define EE 300
#define DIN 768
#define DH 256
#define NREL 26
#define NHEADS 8
#define HDIM 32
#define MTOT (BB*NN)    // 38400
#define NEDGE (BB*EE)   // 38400
#define NHB 150         // histogram blocks (150*256 == NEDGE)

typedef __attribute__((ext_vector_type(8))) short bf16x8;
typedef __attribute__((ext_vector_type(4))) float f32x4;
typedef unsigned short u16;
union BU { uint4 u; bf16x8 v; };

__device__ __forceinline__ unsigned int packbf2(float a, float b) {
    unsigned int ua = __float_as_uint(a);
    unsigned int ub = __float_as_uint(b);
    ua = (ua + 0x7FFFu + ((ua >> 16) & 1u)) >> 16;
    ub = (ub + 0x7FFFu + ((ub >> 16) & 1u)) & 0xFFFF0000u;
    return ua | ub;
}
__device__ __forceinline__ u16 packbf1(float a) {
    unsigned int ua = __float_as_uint(a);
    return (u16)((ua + 0x7FFFu + ((ua >> 16) & 1u)) >> 16);
}
__device__ __forceinline__ unsigned cvtpk(float a, float b) {
    union { __hip_bfloat162 h; unsigned u; } cv;
    cv.h = __float22bfloat162_rn(make_float2(a, b));   // v_cvt_pk_bf16_f32
    return cv.u;
}

// ---------------- atomic-free edge bucketing (counting sort by relation) ----------------
__global__ __launch_bounds__(256) void b_hist(const int* __restrict__ etype,
                                              int* __restrict__ blockhist) {
    __shared__ int hist[NREL];
    const int tid = threadIdx.x;
    if (tid < NREL) hist[tid] = 0;
    __syncthreads();
    atomicAdd(&hist[etype[blockIdx.x * 256 + tid]], 1);   // LDS atomic
    __syncthreads();
    if (tid < NREL) blockhist[blockIdx.x * NREL + tid] = hist[tid];
}

__global__ __launch_bounds__(64) void b_scan(const int* __restrict__ blockhist,
                                             int* __restrict__ blockbase,
                                             int* __restrict__ cnt, int* __restrict__ off) {
    __shared__ int tot[NREL];
    const int r = threadIdx.x;
    if (r < NREL) {
        int run = 0;
        for (int b = 0; b < NHB; ++b) {
            blockbase[b * NREL + r] = run;
            run += blockhist[b * NREL + r];
        }
        tot[r] = run;
        cnt[r] = run;
    }
    __syncthreads();
    __shared__ int offs[NREL + 1];
    if (r == 0) {
        int acc = 0;
        for (int q = 0; q < NREL; ++q) { offs[q] = acc; off[q] = acc; acc += tot[q]; }
        offs[NREL] = acc; off[NREL] = acc;
    }
    __syncthreads();
    if (r < NREL) {
        int o = offs[r];
        for (int b = 0; b < NHB; ++b) blockbase[b * NREL + r] += o;
    }
}

__global__ __launch_bounds__(256) void b_scatter(const int* __restrict__ etype,
                                                 const int* __restrict__ blockbase,
                                                 int* __restrict__ list) {
    __shared__ int wavehist[4][NREL];
    __shared__ int waveoff[4][NREL];
    const int tid = threadIdx.x;
    const int w = tid >> 6, l = tid & 63;
    const int i = blockIdx.x * 256 + tid;
    const int r = etype[i];
    unsigned long long mymask = 0ull;
    #pragma unroll
    for (int q = 0; q < NREL; ++q) {
        unsigned long long m = __ballot(r == q);
        if (l == 0) wavehist[w][q] = __popcll(m);
        if (r == q) mymask = m;
    }
    const int myrank = __popcll(mymask & ((1ull << l) - 1ull));
    __syncthreads();
    if (tid < NREL) {
        int acc = 0;
        #pragma unroll
        for (int ww = 0; ww < 4; ++ww) { waveoff[ww][tid] = acc; acc += wavehist[ww][tid]; }
    }
    __syncthreads();
    list[blockbase[blockIdx.x * NREL + r] + waveoff[w][r] + myrank] = i;
}

// ---------------- casts (+ folded V-tail zeroing in trailing 8 blocks) ----------------
__global__ __launch_bounds__(256) void c_cast8(const float4* __restrict__ in,
                                               uint4* __restrict__ out, int n8) {
    int i = blockIdx.x * 256 + threadIdx.x;
    if (i < n8) {
        float4 f0 = in[2*i], f1 = in[2*i+1];
        uint4 o;
        o.x = packbf2(f0.x, f0.y); o.y = packbf2(f0.z, f0.w);
        o.z = packbf2(f1.x, f1.y); o.w = packbf2(f1.z, f1.w);
        out[i] = o;
    }
}

// Pack weights into MFMA B-fragment order. Blocks >= 2688 zero the V-tail
// fragment chunks (chunks 9/19 per (b,head): jn>=300 slots; k3m overwrites valid part).
__global__ __launch_bounds__(256) void c_cast_w(
    const float* __restrict__ wrel, const float* __restrict__ wl, const float* __restrict__ wq,
    uint4* __restrict__ wrb, uint4* __restrict__ wlb, uint4* __restrict__ wqb,
    uint4* __restrict__ vg4) {
    if (blockIdx.x >= 2688) {
        int t2 = (blockIdx.x - 2688) * 256 + threadIdx.x;   // 0..2047
        #pragma unroll
        for (int j = 0; j < 64; ++j) {
            int m = t2 + j * 2048;            // 0..131071
            int pf = m >> 6, t = m & 63;
            int p = pf >> 1, f = (pf & 1) ? 19 : 9;
            vg4[(size_t)(p * 20 + f) * 64 + t] = make_uint4(0u, 0u, 0u, 0u);
        }
        return;
    }
    int t = blockIdx.x * 256 + threadIdx.x;
    int l = t & 63, fid = t >> 6;
    if (fid < NREL*24*16) {
        int r = fid / 384, rem = fid - r * 384;
        int kf = rem >> 4, nt = rem & 15;
        int k0 = 32*kf + 8*(l >> 4), n = 16*nt + (l & 15);
        const float* p = wrel + ((size_t)r*768 + k0) * 256 + n;
        uint4 o;
        o.x = packbf2(p[0], p[256]); o.y = packbf2(p[512], p[768]);
        o.z = packbf2(p[1024], p[1280]); o.w = packbf2(p[1536], p[1792]);
        wrb[t] = o;
    } else if (fid < NREL*24*16 + 384) {
        int f2 = fid - NREL*24*16;
        int kf = f2 >> 4, nt = f2 & 15;
        int k0 = 32*kf + 8*(l >> 4), n = 16*nt + (l & 15);
        const float* p = wl + (size_t)k0 * 256 + n;
        uint4 o;
        o.x = packbf2(p[0], p[256]); o.y = packbf2(p[512], p[768]);
        o.z = packbf2(p[1024], p[1280]); o.w = packbf2(p[1536], p[1792]);
        wlb[f2*64 + l] = o;
    } else {
        int f2 = fid - NREL*24*16 - 384;   // kf*48 + nt
        int kf = f2 / 48, nt = f2 % 48;
        int e = 16*nt + (l & 15), d0 = 32*kf + 8*(l >> 4);
        const float4* p = (const float4*)(wq + (size_t)e * 256 + d0);
        float4 f0 = p[0], f1 = p[1];
        uint4 o;
        o.x = packbf2(f0.x, f0.y); o.y = packbf2(f0.z, f0.w);
        o.z = packbf2(f1.x, f1.y); o.w = packbf2(f1.z, f1.w);
        wqb[f2*64 + l] = o;
    }
}

// ---------------- MFMA GEMM: h = xb @ wlb + b_rel  (64x128 tile, R7 shape) ----------------
__global__ __launch_bounds__(256) void k1m(
    const uint4* __restrict__ xb, const uint4* __restrict__ wlb,
    const float* __restrict__ brel, float* __restrict__ h) {
    __shared__ uint4 As[512];
    const int tid = threadIdx.x;
    const int m0 = blockIdx.x * 64;
    const int nb = blockIdx.y;
    const int w = tid >> 6, l = tid & 63;
    const int g = l >> 4, q = l & 15;
    int cA[2];
    #pragma unroll
    for (int p = 0; p < 2; ++p) {
        int s = tid + p * 256;
        int fi = s >> 6, l2 = s & 63;
        int kf = fi >> 2, mt = fi & 3;
        int row = m0 + 16*mt + (l2 & 15);
        cA[p] = row * 96 + 4*kf + (l2 >> 4);
    }
    f32x4 acc[4][2];
    #pragma unroll
    for (int a = 0; a < 4; ++a)
        #pragma unroll
        for (int n = 0; n < 2; ++n) acc[a][n] = (f32x4){0.f,0.f,0.f,0.f};

    for (int step = 0; step < 12; ++step) {
        uint4 a0 = xb[cA[0] + step*8];
        uint4 a1 = xb[cA[1] + step*8];
        BU Bf[2][2];
        #pragma unroll
        for (int kf = 0; kf < 2; ++kf)
            #pragma unroll
            for (int nt = 0; nt < 2; ++nt)
                Bf[kf][nt].u = wlb[((step*2 + kf)*16 + nb*8 + w*2 + nt)*64 + l];
        __syncthreads();
        As[tid] = a0; As[tid + 256] = a1;
        __syncthreads();
        #pragma unroll
        for (int kf = 0; kf < 2; ++kf) {
            BU Af[4];
            #pragma unroll
            for (int mt = 0; mt < 4; ++mt) Af[mt].u = As[(kf*4 + mt)*64 + l];
            #pragma unroll
            for (int mt = 0; mt < 4; ++mt)
                #pragma unroll
                for (int nt = 0; nt < 2; ++nt)
                    acc[mt][nt] = __builtin_amdgcn_mfma_f32_16x16x32_bf16(Af[mt].v, Bf[kf][nt].v, acc[mt][nt], 0, 0, 0);
        }
    }
    #pragma unroll
    for (int nt = 0; nt < 2; ++nt) {
        int col = nb*128 + w*32 + nt*16 + q;
        float bias = brel[col];
        #pragma unroll
        for (int mt = 0; mt < 4; ++mt)
            #pragma unroll
            for (int i = 0; i < 4; ++i)
                h[(size_t)(m0 + 16*mt + 4*g + i)*256 + col] = acc[mt][nt][i] + bias;
    }
}

// ------- MFMA per-relation msg GEMM + scatter-add (R7 shape: M=64, N-split z=2) -------
__global__ __launch_bounds__(256) void k2m(
    const uint4* __restrict__ xb, const uint4* __restrict__ wrb,
    const int* __restrict__ src, const int* __restrict__ dst,
    const int* __restrict__ cnt, const int* __restrict__ off,
    const int* __restrict__ list, float* __restrict__ h) {
    __shared__ uint4 As[512];
    __shared__ int arow_s[64];
    __shared__ int drow_s[64];
    const int r = blockIdx.y;
    const int c_total = cnt[r];
    const int t0 = blockIdx.x * 64;
    if (t0 >= c_total) return;
    const int nb = blockIdx.z;
    const int tid = threadIdx.x;
    if (tid < 64) {
        int e = t0 + tid;
        int ar = 0, dr = -1;
        if (e < c_total) {
            int eid = list[off[r] + e];
            int b = eid / EE;
            ar = b * NN + src[eid];
            dr = b * NN + dst[eid];
        }
        arow_s[tid] = ar; drow_s[tid] = dr;
    }
    __syncthreads();
    const int w = tid >> 6, l = tid & 63;
    const int g = l >> 4, q = l & 15;
    int cA[2];
    #pragma unroll
    for (int p = 0; p < 2; ++p) {
        int s = tid + p * 256;
        int fi = s >> 6, l2 = s & 63;
        int kf = fi >> 2, mt = fi & 3;
        int row = arow_s[16*mt + (l2 & 15)];
        cA[p] = row * 96 + 4*kf + (l2 >> 4);
    }
    const uint4* wb = wrb + (size_t)r * 24*16*64;
    f32x4 acc[4][2];
    #pragma unroll
    for (int a = 0; a < 4; ++a)
        #pragma unroll
        for (int n = 0; n < 2; ++n) acc[a][n] = (f32x4){0.f,0.f,0.f,0.f};

    for (int step = 0; step < 12; ++step) {
        uint4 a0 = xb[cA[0] + step*8];
        uint4 a1 = xb[cA[1] + step*8];
        BU Bf[2][2];
        #pragma unroll
        for (int kf = 0; kf < 2; ++kf)
            #pragma unroll
            for (int nt = 0; nt < 2; ++nt)
                Bf[kf][nt].u = wb[((step*2 + kf)*16 + nb*8 + w*2 + nt)*64 + l];
        __syncthreads();
        As[tid] = a0; As[tid + 256] = a1;
        __syncthreads();
        #pragma unroll
        for (int kf = 0; kf < 2; ++kf) {
            BU Af[4];
            #pragma unroll
            for (int mt = 0; mt < 4; ++mt) Af[mt].u = As[(kf*4 + mt)*64 + l];
            #pragma unroll
            for (int mt = 0; mt < 4; ++mt)
                #pragma unroll
                for (int nt = 0; nt < 2; ++nt)
                    acc[mt][nt] = __builtin_amdgcn_mfma_f32_16x16x32_bf16(Af[mt].v, Bf[kf][nt].v, acc[mt][nt], 0, 0, 0);
        }
    }
    #pragma unroll
    for (int mt = 0; mt < 4; ++mt)
        #pragma unroll
        for (int i = 0; i < 4; ++i) {
            int dr = drow_s[16*mt + 4*g + i];
            if (dr >= 0) {
                #pragma unroll
                for (int nt = 0; nt < 2; ++nt)
                    atomicAdd(&h[(size_t)dr*256 + nb*128 + w*32 + nt*16 + q], acc[mt][nt][i]);
            }
        }
}

// ---------------- MFMA qkv = hb @ wqb^T + bias; outputs written DIRECTLY in MFMA
// fragment order per (batch, head) -- R7 shape, grid (600,6).
__global__ __launch_bounds__(256) void k3m(
    const uint4* __restrict__ hb, const uint4* __restrict__ wqb,
    const float* __restrict__ bq,
    u16* __restrict__ qg, u16* __restrict__ kg, u16* __restrict__ vg) {
    __shared__ uint4 As[512];
    const int tid = threadIdx.x;
    const int m0 = blockIdx.x * 64;
    const int nb = blockIdx.y;           // 6 n-spans of 128
    const int w = tid >> 6, l = tid & 63;
    const int g = l >> 4, q = l & 15;
    int cA[2];
    #pragma unroll
    for (int p = 0; p < 2; ++p) {
        int s = tid + p * 256;
        int fi = s >> 6, l2 = s & 63;
        int kf = fi >> 2, mt = fi & 3;
        int row = m0 + 16*mt + (l2 & 15);
        cA[p] = row * 32 + 4*kf + (l2 >> 4);
    }
    f32x4 acc[4][2];
    #pragma unroll
    for (int a = 0; a < 4; ++a)
        #pragma unroll
        for (int n = 0; n < 2; ++n) acc[a][n] = (f32x4){0.f,0.f,0.f,0.f};

    for (int step = 0; step < 4; ++step) {
        uint4 a0 = hb[cA[0] + step*8];
        uint4 a1 = hb[cA[1] + step*8];
        BU Bf[2][2];
        #pragma unroll
        for (int kf = 0; kf < 2; ++kf)
            #pragma unroll
            for (int nt = 0; nt < 2; ++nt)
                Bf[kf][nt].u = wqb[((step*2 + kf)*48 + nb*8 + w*2 + nt)*64 + l];
        __syncthreads();
        As[tid] = a0; As[tid + 256] = a1;
        __syncthreads();
        #pragma unroll
        for (int kf = 0; kf < 2; ++kf) {
            BU Af[4];
            #pragma unroll
            for (int mt = 0; mt < 4; ++mt) Af[mt].u = As[(kf*4 + mt)*64 + l];
            #pragma unroll
            for (int mt = 0; mt < 4; ++mt)
                #pragma unroll
                for (int nt = 0; nt < 2; ++nt)
                    acc[mt][nt] = __builtin_amdgcn_mfma_f32_16x16x32_bf16(Af[mt].v, Bf[kf][nt].v, acc[mt][nt], 0, 0, 0);
        }
    }
    #pragma unroll
    for (int nt = 0; nt < 2; ++nt) {
        int e = nb*128 + w*32 + nt*16 + q;
        float bias = bq[e];
        int region = e >> 8;              // 0=Q,1=K,2=V
        int hh = (e & 255) >> 5;
        int d  = e & 31;
        u16* outb = (region == 0) ? qg : (region == 1) ? kg : vg;
        #pragma unroll
        for (int mt = 0; mt < 4; ++mt) {
            #pragma unroll
            for (int i = 0; i < 4; ++i) {
                int j = m0 + 16*mt + 4*g + i;
                int b_ = j / 300;
                int jn = j - b_ * 300;
                u16 val = packbf1(acc[mt][nt][i] + bias);
                size_t byte;
                if (region < 2) {
                    int word = ((b_*8 + hh)*19 + (jn >> 4))*64 + 16*(d >> 3) + (jn & 15);
                    byte = (size_t)word*16 + (size_t)(d & 7)*2;
                } else {
                    int word = ((b_*8 + hh)*20 + (d >> 4)*10 + (jn >> 5))*64 + 16*((jn >> 3) & 3) + (d & 15);
                    byte = (size_t)word*16 + (size_t)(jn & 7)*2;
                }
                *(u16*)((char*)outb + byte) = val;
            }
        }
    }
}

// ------- MFMA flash attention, no-max softmax (exp2 direct), batched P-transpose -------
__global__ __launch_bounds__(256) void k4_attn(
    const uint4* __restrict__ qg, const uint4* __restrict__ kg,
    const uint4* __restrict__ vg, float* __restrict__ pooled) {
    __shared__ uint4 kf_s[19*64];
    __shared__ uint4 vt_s[20*64];
    __shared__ __align__(16) u16 pbuf[4][2560];   // 5KB per wave: 5 chunks x 1KB
    __shared__ float pool_lds[4][32];
    const int bh = blockIdx.x;
    const int tid = threadIdx.x;
    for (int s = tid; s < 19*64; s += 256) kf_s[s] = kg[(size_t)bh*19*64 + s];
    for (int s = tid; s < 20*64; s += 256) vt_s[s] = vg[(size_t)bh*20*64 + s];
    __syncthreads();

    const int w = tid >> 6, l = tid & 63;
    const int g = l >> 4, q = l & 15;
    char* pwbase = (char*)pbuf[w] + 256*(g >> 1) + 16*q + 8*(g & 1);
    const uint4* prd = (const uint4*)pbuf[w];

    const float c1 = 0.17677669529663687f * 1.4426950408889634f;  // (1/sqrt(32))*log2(e)
    float pool[8] = {0.f,0.f,0.f,0.f,0.f,0.f,0.f,0.f};

    for (int qt = w; qt < 19; qt += 4) {
        const int qrow = qt * 16 + q;
        BU uq; uq.u = qg[(size_t)(bh*19 + qt)*64 + l];
        float lsum = 0.f;
        f32x4 ctx0 = {0.f,0.f,0.f,0.f}, ctx1 = {0.f,0.f,0.f,0.f};

        #pragma unroll
        for (int half = 0; half < 2; ++half) {
            #pragma unroll
            for (int jj = 0; jj < 10; ++jj) {
                const int jt = half*10 + jj;
                uint2 pk = make_uint2(0u, 0u);
                if (jt < 19) {
                    BU uk; uk.u = kf_s[jt*64 + l];
                    f32x4 z = {0.f,0.f,0.f,0.f};
                    f32x4 s4 = __builtin_amdgcn_mfma_f32_16x16x32_bf16(uk.v, uq.v, z, 0, 0, 0);
                    float p0 = exp2f(s4[0]*c1);
                    float p1 = exp2f(s4[1]*c1);
                    float p2 = exp2f(s4[2]*c1);
                    float p3 = exp2f(s4[3]*c1);
                    if (jt == 18 && g == 3) { p0 = 0.f; p1 = 0.f; p2 = 0.f; p3 = 0.f; }
                    lsum += (p0 + p1) + (p2 + p3);
                    pk.x = cvtpk(p0, p1);
                    pk.y = cvtpk(p2, p3);
                }
                *(uint2*)(pwbase + 512*jj) = pk;
            }
            #pragma unroll
            for (int cc = 0; cc < 5; ++cc) {
                const int cg = half*5 + cc;
                BU up;  up.u  = prd[cc*64 + l];
                BU uv0; uv0.u = vt_s[cg*64 + l];
                BU uv1; uv1.u = vt_s[(10 + cg)*64 + l];
                ctx0 = __builtin_amdgcn_mfma_f32_16x16x32_bf16(uv0.v, up.v, ctx0, 0, 0, 0);
                ctx1 = __builtin_amdgcn_mfma_f32_16x16x32_bf16(uv1.v, up.v, ctx1, 0, 0, 0);
            }
        }
        lsum += __shfl_xor(lsum, 16);
        lsum += __shfl_xor(lsum, 32);
        if (qrow < NN) {
            float inv = 1.0f / lsum;
            pool[0] += ctx0[0] * inv; pool[1] += ctx0[1] * inv;
            pool[2] += ctx0[2] * inv; pool[3] += ctx0[3] * inv;
            pool[4] += ctx1[0] * inv; pool[5] += ctx1[1] * inv;
            pool[6] += ctx1[2] * inv; pool[7] += ctx1[3] * inv;
        }
    }

    #pragma unroll
    for (int i = 0; i < 8; ++i) {
        float v = pool[i];
        v += __shfl_xor(v, 1); v += __shfl_xor(v, 2);
        v += __shfl_xor(v, 4); v += __shfl_xor(v, 8);
        pool[i] = v;
    }
    if (q == 0) {
        #pragma unroll
        for (int dt = 0; dt < 2; ++dt)
            #pragma unroll
            for (int i = 0; i < 4; ++i)
                pool_lds[w][dt * 16 + 4 * g + i] = pool[dt * 4 + i];
    }
    __syncthreads();
    if (tid < 32) {
        int b = bh >> 3, hh = bh & 7;
        float s = pool_lds[0][tid] + pool_lds[1][tid] + pool_lds[2][tid] + pool_lds[3][tid];
        pooled[(size_t)b * DH + hh * HDIM + tid] = s * (1.0f / 300.0f);
    }
}

// ------- out = ((pooled @ out_proj^T + bo) @ mlp^T + bm) -------
__global__ __launch_bounds__(256) void k5_head(
    const float* __restrict__ pooled, const float* __restrict__ wo, const float* __restrict__ bo,
    const float* __restrict__ wm, const float* __restrict__ bm, float* __restrict__ out) {
    __shared__ float pc[DH];
    __shared__ float t1[DH];
    const int b = blockIdx.x, tid = threadIdx.x;
    pc[tid] = pooled[(size_t)b * DH + tid];
    __syncthreads();
    float acc = bo[tid];
    for (int d = 0; d < DH; ++d) acc += pc[d] * wo[(size_t)tid * DH + d];
    t1[tid] = acc;
    __syncthreads();
    float acc2 = bm[tid];
    for (int e2 = 0; e2 < DH; ++e2) acc2 += t1[e2] * wm[(size_t)tid * DH + e2];
    out[(size_t)b * DH + tid] = acc2;
}

extern "C" void kernel_launch(void* const* d_in, const int* in_sizes, int n_in,
                              void* d_out, int out_size, void* d_ws, size_t ws_size,
                              hipStream_t stream) {
    (void)in_sizes; (void)n_in; (void)out_size; (void)ws_size;
    const float* x     = (const float*)d_in[0];
    const int*   src   = (const int*)d_in[1];
    const int*   dst   = (const int*)d_in[2];
    const int*   etype = (const int*)d_in[3];
    const float* wrel  = (const float*)d_in[4];
    const float* wloop = (const float*)d_in[5];
    const float* brel  = (const float*)d_in[6];
    const float* wq    = (const float*)d_in[7];
    const float* bq    = (const float*)d_in[8];
    const float* wo    = (const float*)d_in[9];
    const float* bo    = (const float*)d_in[10];
    const float* wm    = (const float*)d_in[11];
    const float* bm    = (const float*)d_in[12];
    float* out = (float*)d_out;

    char* W = (char*)d_ws;
    float* h      = (float*)W;                          // 39,321,600 B
    u16*   xb     = (u16*)(W + 39321600ull);            // 58,982,400 B (dead after k2m)
    u16*   qg     = xb;                                 // 19,922,944 B (k3m writes after xb dead)
    u16*   kg     = (u16*)(W + 39321600ull + 19922944ull);  // 19,922,944 B
    u16*   hb     = (u16*)(W + 39321600ull + 58982400ull);  // 19,660,800 B
    uint4* wrb    = (uint4*)(W + 39321600ull + 58982400ull + 19660800ull);  // 10,223,616
    uint4* wlb    = (uint4*)((char*)wrb + 10223616ull);
    uint4* wqb    = (uint4*)((char*)wlb + 393216ull);
    float* pooled = (float*)((char*)wqb + 393216ull);
    int*   ibase  = (int*)((char*)pooled + 131072ull);
    int*   cnt    = ibase;                               // 32
    int*   off    = ibase + 32;                          // 32
    int*   list   = ibase + 64;                          // 38400
    int*   blockhist = list + NEDGE;                     // 150*26
    int*   blockbase = blockhist + NHB*NREL;             // 150*26
    // vg in its own region past the index data (R8-verified within ws_size)
    u16*   vg = (u16*)((char*)(blockbase + NHB*NREL) + 256);
    vg = (u16*)(((uintptr_t)vg + 255) & ~(uintptr_t)255);

    b_hist<<<NHB, 256, 0, stream>>>(etype, blockhist);
    b_scan<<<1, 64, 0, stream>>>(blockhist, blockbase, cnt, off);
    b_scatter<<<NHB, 256, 0, stream>>>(etype, blockbase, list);

    c_cast8<<<14400, 256, 0, stream>>>((const float4*)x, (uint4*)xb, 3686400);
    c_cast_w<<<2696, 256, 0, stream>>>(wrel, wloop, wq, wrb, wlb, wqb, (uint4*)vg);

    k1m<<<dim3(600, 2), 256, 0, stream>>>((const uint4*)xb, wlb, brel, h);
    k2m<<<dim3(32, 26, 2), 256, 0, stream>>>((const uint4*)xb, wrb, src, dst, cnt, off, list, h);
    c_cast8<<<4800, 256, 0, stream>>>((const float4*)h, (uint4*)hb, 1228800);
    k3m<<<dim3(600, 6), 256, 0, stream>>>((const uint4*)hb, wqb, bq, qg, kg, vg);
    k4_attn<<<BB * NHEADS, 256, 0, stream>>>((const uint4*)qg, (const uint4*)kg, (const uint4*)vg, pooled);
    k5_head<<<BB, 256, 0, stream>>>(pooled, wo, bo, wm, bm, out);
}